// Round 15
// baseline (3109.699 us; speedup 1.0000x reference)
//
#include <hip/hip_runtime.h>

typedef __attribute__((ext_vector_type(8))) short short8;   // 8 bf16 (4 VGPRs)
typedef __attribute__((ext_vector_type(4))) float f32x4;
typedef __attribute__((ext_vector_type(4))) unsigned short ushort4_;

constexpr int B_ = 32;
constexpr int N_ = 1024;
constexpr int C_ = 64;
constexpr int T_ = 24;
constexpr int F_ = 64;
constexpr int CT_ = C_ * T_;     // 1536
constexpr int KS_ = 3072;        // stacked K = 3*1024

__device__ __forceinline__ float sigmoidf_(float x) {
    return 1.0f / (1.0f + __expf(-x));
}
__device__ __forceinline__ unsigned short f2b(float f) {   // RNE f32->bf16
    union { float f; unsigned u; } v; v.f = f;
    unsigned r = v.u + 0x7FFFu + ((v.u >> 16) & 1u);
    return (unsigned short)(r >> 16);
}
__device__ __forceinline__ float b2f(unsigned short h) {
    union { unsigned u; float f; } v; v.u = ((unsigned)h) << 16; return v.f;
}
__device__ __forceinline__ void gload_lds16(const unsigned short* g, unsigned short* l) {
    __builtin_amdgcn_global_load_lds(
        (const __attribute__((address_space(1))) unsigned int*)g,
        (__attribute__((address_space(3))) unsigned int*)l, 16, 0, 0);
}

// ---------------- fused x reductions: rhs_t + U1-partial (one x read) ----------------
__global__ __launch_bounds__(256) void k_xreduce(const float* __restrict__ x,
        const float* __restrict__ U1, const float* __restrict__ U3,
        float* __restrict__ rhs_t, float* __restrict__ partial) {
    int b = blockIdx.y, g0 = blockIdx.x * 32;
    int tid = threadIdx.x;
    __shared__ float xr[8 * CT_];                        // 48 KB
    __shared__ float u3s[C_];
    if (tid < C_) u3s[tid] = U3[tid];
    float pacc[6] = {0, 0, 0, 0, 0, 0};
    for (int ph = 0; ph < 4; ++ph) {
        int n0 = g0 + ph * 8;
        __syncthreads();                                 // prev phase LDS reads done
        const float4* x4 = (const float4*)(x + ((size_t)(b * N_ + n0)) * CT_);
#pragma unroll
        for (int e = 0; e < 12; ++e) {
            int i4 = e * 256 + tid;
            float4 v = x4[i4];
            int i = i4 * 4;
            xr[i] = v.x; xr[i + 1] = v.y; xr[i + 2] = v.z; xr[i + 3] = v.w;
        }
        __syncthreads();
        if (tid < 192) {
            int n = tid / 24, t = tid % 24;
            const float* xn = xr + n * CT_ + t;
            float acc = 0.f;
#pragma unroll
            for (int c = 0; c < C_; ++c) acc += u3s[c] * xn[c * 24];
            rhs_t[((size_t)(b * N_ + n0 + n)) * T_ + t] = acc;
        }
#pragma unroll
        for (int n = 0; n < 8; ++n) {
            float u = U1[n0 + n];                        // uniform -> scalar
            const float* xn = xr + n * CT_;
#pragma unroll
            for (int e = 0; e < 6; ++e) pacc[e] += u * xn[tid + e * 256];
        }
    }
    float* pp = partial + ((size_t)(b * 32 + blockIdx.x)) * CT_;
#pragma unroll
    for (int e = 0; e < 6; ++e) pp[tid + e * 256] = pacc[e];
}

__global__ void k_lhs_reduce(const float* __restrict__ partial, float* __restrict__ lhs_t0) {
    int idx = blockIdx.x * 256 + threadIdx.x;
    if (idx >= B_ * CT_) return;
    int b = idx / CT_, flat = idx % CT_;
    float acc = 0.f;
#pragma unroll
    for (int ch = 0; ch < 32; ++ch) acc += partial[((size_t)(b * 32 + ch)) * CT_ + flat];
    lhs_t0[idx] = acc;
}

__global__ void k_lhs_t(const float* __restrict__ lhs_t0, const float* __restrict__ U2,
                        float* __restrict__ lhs_t) {
    int idx = blockIdx.x * 256 + threadIdx.x;
    if (idx >= B_ * T_ * N_) return;
    int n2 = idx % N_;
    int t = (idx / N_) % T_;
    int b = idx / (T_ * N_);
    const float* l0 = lhs_t0 + (size_t)b * CT_;
    float acc = 0.f;
#pragma unroll
    for (int c = 0; c < C_; ++c) acc += l0[c * T_ + t] * U2[c * N_ + n2];
    lhs_t[idx] = acc;
}

// prod_t partials: ptp[b][ch][i][u] = sum_{n in ch} lhs_t[b,i,n]*rhs_t[b,n,u]
__global__ __launch_bounds__(576) void k_prodt(const float* __restrict__ lhs_t,
        const float* __restrict__ rhs_t, float* __restrict__ ptp) {
    int b = blockIdx.y, ch = blockIdx.x;
    int tid = threadIdx.x;
    __shared__ float lt[24][128];
    __shared__ float rt[128][25];
    int n0 = ch * 128;
    for (int e = tid; e < 24 * 128; e += 576) {
        int i = e >> 7, nn = e & 127;
        lt[i][nn] = lhs_t[((size_t)b * T_ + i) * N_ + n0 + nn];
    }
    const float* rg = rhs_t + ((size_t)b * N_ + n0) * T_;
    for (int e = tid; e < 128 * 24; e += 576) {
        int nn = e / 24, t = e - nn * 24;
        rt[nn][t] = rg[e];
    }
    __syncthreads();
    int i = tid / 24, u = tid - (tid / 24) * 24;
    float acc = 0.f;
#pragma unroll 8
    for (int nn = 0; nn < 128; ++nn) acc += lt[i][nn] * rt[nn][u];
    ptp[(((size_t)b * 8 + ch) * 24 + i) * 24 + u] = acc;
}

__global__ void k_temporal_E(const float* __restrict__ ptp,
                             const float* __restrict__ b_e, const float* __restrict__ V_e,
                             float* __restrict__ E) {
    int b = blockIdx.x;
    int tid = threadIdx.x;                               // 576 threads
    int i = tid / T_, u = tid % T_;
    __shared__ float sig[T_][T_];
    __shared__ float e0s[T_][T_];
    __shared__ float mcol[T_], scol[T_];
    float acc = 0.f;
#pragma unroll
    for (int ch = 0; ch < 8; ++ch)
        acc += ptp[(((size_t)b * 8 + ch) * 24 + i) * 24 + u];
    sig[i][u] = sigmoidf_(acc + b_e[i * T_ + u]);
    __syncthreads();
    int j = u;
    float e0 = 0.f;
#pragma unroll
    for (int kk = 0; kk < T_; ++kk) e0 += sig[i][kk] * V_e[j * T_ + kk];
    e0s[i][j] = e0;
    __syncthreads();
    if (tid < T_) {
        float mx = -1e30f;
        for (int ii = 0; ii < T_; ++ii) mx = fmaxf(mx, e0s[ii][tid]);
        float s = 0.f;
        for (int ii = 0; ii < T_; ++ii) s += __expf(e0s[ii][tid] - mx);
        mcol[tid] = mx; scol[tid] = s;
    }
    __syncthreads();
    E[(size_t)b * T_ * T_ + i * T_ + j] = __expf(e0s[i][j] - mcol[j]) / scol[j];
}

// ---------------- fused: x_TAt (in-register) -> spatial prep + xTt emit ----------------
__global__ __launch_bounds__(256) void k_tspatial(const float* __restrict__ x,
        const float* __restrict__ E, const float* __restrict__ W1g,
        const float* __restrict__ W2, const float* __restrict__ W3g,
        float* __restrict__ lhs_s, float* __restrict__ rhs_s,
        unsigned short* __restrict__ xTt) {
    int b = blockIdx.y;
    int n0 = blockIdx.x * 4;
    int tid = threadIdx.x;
    __shared__ float Es[T_ * T_];
    __shared__ float W1s[T_];
    __shared__ float W2s[C_ * T_];
    __shared__ float xr[4][64][25];                      // staged x, then reused for w3*u
    __shared__ float l0s[4][64];
    for (int e = tid; e < T_ * T_; e += 256) Es[e] = E[(size_t)b * T_ * T_ + e];
    for (int e = tid; e < C_ * T_; e += 256) W2s[e] = W2[e];
    if (tid < T_) W1s[tid] = W1g[tid];
    size_t base = ((size_t)b * N_ + n0) * CT_;
    const float4* x4 = (const float4*)(x + base);
#pragma unroll
    for (int i = 0; i < 6; ++i) {
        int e4 = i * 256 + tid;
        float4 v = x4[e4];
        int e = e4 * 4;
        int nl = e / CT_; int rem = e - nl * CT_; int c = rem / 24; int tl = rem - c * 24;
        xr[nl][c][tl] = v.x; xr[nl][c][tl + 1] = v.y;
        xr[nl][c][tl + 2] = v.z; xr[nl][c][tl + 3] = v.w;
    }
    __syncthreads();
    int nl = tid >> 6, c = tid & 63;
    float xv[T_];
#pragma unroll
    for (int t = 0; t < T_; ++t) xv[t] = xr[nl][c][t];
    // emit xTt[b][t][n][c] bf16 from staged x (coalesced 128B chunks)
#pragma unroll
    for (int i = 0; i < 24; ++i) {
        int idx = i * 256 + tid;
        int cc = idx & 63, nn = (idx >> 6) & 3, t = idx >> 8;
        xTt[((size_t)(b * T_ + t) * N_ + n0 + nn) * 64 + cc] = f2b(xr[nn][cc][t]);
    }
    float w3 = W3g[c];
    float u[T_];
#pragma unroll
    for (int j = 0; j < T_; ++j) {
        float a = 0.f;
#pragma unroll
        for (int t = 0; t < T_; ++t) a += xv[t] * Es[t * T_ + j];
        u[j] = a;
    }
    float l0 = 0.f;
#pragma unroll
    for (int j = 0; j < T_; ++j) l0 += u[j] * W1s[j];
    __syncthreads();                                     // xTt-emit LDS reads done
#pragma unroll
    for (int j = 0; j < T_; ++j) xr[nl][c][j] = w3 * u[j];
    l0s[nl][c] = l0;
    __syncthreads();
    if (tid < 4 * T_) {
        int t = tid % T_, g = tid / T_;
        float racc = 0.f, lacc = 0.f;
        for (int cc = 0; cc < 64; ++cc) {
            racc += xr[g][cc][t];
            lacc += l0s[g][cc] * W2s[cc * T_ + t];
        }
        rhs_s[((size_t)b * T_ + t) * N_ + n0 + g] = racc;
        lhs_s[((size_t)(b * N_ + n0 + g)) * T_ + t] = lacc;
    }
}

// ---------------- converters / builders ----------------
__global__ void k_cvt_bf(const float* __restrict__ v, unsigned short* __restrict__ o) {
    int i = blockIdx.x * 256 + threadIdx.x;
    o[i] = f2b(v[i]);
}

// Wcat[ft][k], k = sel*64+c: sel 0..2 -> tc_w taps, sel 3 -> rc_w.  bf16 [64][256]
__global__ void k_wcat(const float* __restrict__ tc_w, const float* __restrict__ rc_w,
                       unsigned short* __restrict__ Wcat) {
    int i = blockIdx.x * 256 + threadIdx.x;              // over 64*256
    if (i >= F_ * 256) return;
    int ft = i >> 8, k = i & 255;
    int sel = k >> 6, c = k & 63;
    float v = (sel < 3) ? tc_w[(ft * C_ + c) * 3 + sel] : rc_w[ft * C_ + c];
    Wcat[i] = f2b(v);
}

// Thp[k*64+f][c] (bf16) = Theta[k][c][f]   -- A-operand for k_yTmm
__global__ void k_thp(const float* __restrict__ Theta, unsigned short* __restrict__ Thp) {
    int i = blockIdx.x * 256 + threadIdx.x;              // over 192*64
    if (i >= 192 * 64) return;
    int kf = i >> 6, c = i & 63;
    int k = kf >> 6, f = kf & 63;
    Thp[i] = f2b(Theta[((size_t)k * 64 + c) * 64 + f]);
}

// sigA[b][i][k] (bf16) = sigmoid(dot24(lhs_s[b,i,:], rhs_s[b,:,k]) + b_s[i,k])
__global__ __launch_bounds__(256) void k_sig(const float* __restrict__ lhs_s,
        const float* __restrict__ rhs_s, const float* __restrict__ b_s,
        unsigned short* __restrict__ sigA) {
    int b = blockIdx.z, i0 = blockIdx.y * 64, k0 = blockIdx.x * 256;
    int tid = threadIdx.x;
    __shared__ float lh[64 * T_];
    __shared__ float rh[T_][256];
    for (int e = tid; e < 64 * T_; e += 256) lh[e] = lhs_s[((size_t)b * N_ + i0) * T_ + e];
#pragma unroll
    for (int t = 0; t < T_; ++t) rh[t][tid] = rhs_s[((size_t)b * T_ + t) * N_ + k0 + tid];
    __syncthreads();
    int kg = k0 + tid;
    for (int ii = 0; ii < 64; ++ii) {
        float acc = b_s[(size_t)(i0 + ii) * N_ + kg];
#pragma unroll
        for (int t = 0; t < T_; ++t) acc += lh[ii * T_ + t] * rh[t][tid];
        sigA[((size_t)b * N_ + i0 + ii) * N_ + kg] = f2b(sigmoidf_(acc));
    }
}

// ---------------- yT via MFMA, coalesced stores through LDS C-tile ----------------
__global__ __launch_bounds__(256) void k_yTmm(const unsigned short* __restrict__ xTt,
        const unsigned short* __restrict__ Thp, unsigned short* __restrict__ yT) {
    int bt = blockIdx.y;
    int b = bt / T_, t = bt - b * T_;
    int m0 = blockIdx.x * 128;
    int tid = threadIdx.x;
    int lane = tid & 63, wv = tid >> 6;
    __shared__ __align__(16) char smem[50688];
    unsigned short* Asb = (unsigned short*)smem;             // [192*64] (live whole kernel)
    unsigned short* Bsb = (unsigned short*)(smem + 24576);   // [128*64]
    unsigned short* Cl  = (unsigned short*)(smem + 24576);   // [96][136] (after Bsb dead)
#pragma unroll
    for (int e = 0; e < 6; ++e) {                        // stage Thp (24KB)
        int chunk = e * 256 + tid;
        int row = chunk >> 3, slot = chunk & 7;
        int gslot = slot ^ (row & 7);
        gload_lds16(Thp + row * 64 + gslot * 8, &Asb[chunk * 8]);
    }
    const unsigned short* Bg = xTt + ((size_t)bt * N_ + m0) * 64;
#pragma unroll
    for (int e = 0; e < 4; ++e) {                        // stage B (16KB)
        int chunk = e * 256 + tid;
        int row = chunk >> 3, slot = chunk & 7;
        int gslot = slot ^ (row & 7);
        gload_lds16(Bg + (size_t)row * 64 + gslot * 8, &Bsb[chunk * 8]);
    }
    __syncthreads();                                     // drains vmcnt

    short8 bf[2][2];
#pragma unroll
    for (int ni = 0; ni < 2; ++ni)
#pragma unroll
        for (int kk = 0; kk < 2; ++kk) {
            int r = wv * 32 + ni * 16 + (lane & 15);
            int slot = (kk * 4 + (lane >> 4)) ^ (r & 7);
            bf[ni][kk] = *(const short8*)&Bsb[r * 64 + slot * 8];
        }
    f32x4 acc[12][2];
#pragma unroll
    for (int mi = 0; mi < 12; ++mi)
#pragma unroll
        for (int ni = 0; ni < 2; ++ni) acc[mi][ni] = (f32x4){0.f, 0.f, 0.f, 0.f};
#pragma unroll
    for (int mi = 0; mi < 12; ++mi) {
        short8 af[2];
#pragma unroll
        for (int kk = 0; kk < 2; ++kk) {
            int r = mi * 16 + (lane & 15);
            int slot = (kk * 4 + (lane >> 4)) ^ (r & 7);
            af[kk] = *(const short8*)&Asb[r * 64 + slot * 8];
        }
#pragma unroll
        for (int kk = 0; kk < 2; ++kk)
#pragma unroll
            for (int ni = 0; ni < 2; ++ni)
                acc[mi][ni] = __builtin_amdgcn_mfma_f32_16x16x32_bf16(
                    af[kk], bf[ni][kk], acc[mi][ni], 0, 0, 0);
    }
#pragma unroll
    for (int h = 0; h < 2; ++h) {
        __syncthreads();
#pragma unroll
        for (int mi2 = 0; mi2 < 6; ++mi2) {
            int mi = h * 6 + mi2;
#pragma unroll
            for (int r = 0; r < 4; ++r) {
                int row = mi2 * 16 + (lane >> 4) * 4 + r;
#pragma unroll
                for (int ni = 0; ni < 2; ++ni)
                    Cl[row * 136 + wv * 32 + ni * 16 + (lane & 15)] = f2b(acc[mi][ni][r]);
            }
        }
        __syncthreads();
#pragma unroll
        for (int e = 0; e < 6; ++e) {
            int idx = e * 256 + tid;
            int row = idx >> 4, seg = idx & 15;
            int kf = h * 96 + row;
            int k = kf >> 6, f = kf & 63;
            uint4 v = *(const uint4*)&Cl[row * 136 + seg * 8];
            *(uint4*)&yT[((size_t)b * CT_ + f * T_ + t) * KS_ + k * N_ + m0 + seg * 8] = v;
        }
    }
}

// online softmax stats over axis m of S[b,m,i] (bf16): mst[b*N+i] = (max, 1/sum)
__global__ void k_smstats(const unsigned short* __restrict__ S, float2* __restrict__ mst) {
    int b = blockIdx.y;
    int jj = threadIdx.x % 64;
    int ig = threadIdx.x / 64;
    int j = blockIdx.x * 64 + jj;
    __shared__ float rm[4][64], rs[4][64];
    float m = -1e30f, s = 0.f;
    for (int i = ig; i < N_; i += 4) {
        float v = b2f(S[((size_t)b * N_ + i) * N_ + j]);
        float mn = fmaxf(m, v);
        s = s * __expf(m - mn) + __expf(v - mn);
        m = mn;
    }
    rm[ig][jj] = m; rs[ig][jj] = s;
    __syncthreads();
    if (ig == 0) {
        float M = rm[0][jj], SS = rs[0][jj];
#pragma unroll
        for (int g = 1; g < 4; ++g) {
            float mg = rm[g][jj];
            float mn = fmaxf(M, mg);
            SS = SS * __expf(M - mn) + rs[g][jj] * __expf(mg - mn);
            M = mn;
        }
        mst[(size_t)b * N_ + j] = make_float2(M, 1.f / SS);
    }
}

// chebSt[b][i][k*1024+m] (bf16) = chb[k][m][i] * softmax(S)[b][m][i]  (bf16 reads)
__global__ __launch_bounds__(256) void k_chebSt(const unsigned short* __restrict__ chb,
        const unsigned short* __restrict__ S, const float2* __restrict__ mst,
        unsigned short* __restrict__ cs) {
    int b = blockIdx.z, i0 = blockIdx.y * 64, m0 = blockIdx.x * 64;
    int tid = threadIdx.x;
    __shared__ float st[64][65];
    __shared__ float cb[64][65];
    __shared__ float2 sst[64];
    if (tid < 64) sst[tid] = mst[(size_t)b * N_ + i0 + tid];
#pragma unroll
    for (int e = 0; e < 4; ++e) {
        int idx4 = e * 256 + tid;
        int mm = idx4 >> 4, ii0 = (idx4 & 15) * 4;
        ushort4_ v = *(const ushort4_*)&S[((size_t)b * N_ + m0 + mm) * N_ + i0 + ii0];
        st[mm][ii0] = b2f(v.x); st[mm][ii0 + 1] = b2f(v.y);
        st[mm][ii0 + 2] = b2f(v.z); st[mm][ii0 + 3] = b2f(v.w);
    }
    for (int k = 0; k < 3; ++k) {
        __syncthreads();
#pragma unroll
        for (int e = 0; e < 4; ++e) {
            int idx4 = e * 256 + tid;
            int mm = idx4 >> 4, ii0 = (idx4 & 15) * 4;
            ushort4_ v = *(const ushort4_*)&chb[((size_t)k * N_ + m0 + mm) * N_ + i0 + ii0];
            cb[mm][ii0] = b2f(v.x); cb[mm][ii0 + 1] = b2f(v.y);
            cb[mm][ii0 + 2] = b2f(v.z); cb[mm][ii0 + 3] = b2f(v.w);
        }
        __syncthreads();
#pragma unroll
        for (int e = 0; e < 16; ++e) {
            int idx = e * 256 + tid; int mm = idx & 63, ii = idx >> 6;
            float sm = __expf(st[mm][ii] - sst[ii].x) * sst[ii].y;
            cs[((size_t)b * N_ + i0 + ii) * KS_ + k * N_ + m0 + mm] =
                f2b(sm * cb[mm][ii]);
        }
    }
}

// ---------------- 256x256-tile MFMA GEMM, register-held deep pipeline ----------------
// Per K-tile: [STAGE(kt+2)->buf[cur] (its data lives in regs)] [vmcnt(8)] [barA]
// [READF next tile -> other frag set] [64 MFMA on current frags] [lgkm(0)] [barB].
// Race-freedom: reads of buf[cur] completed+lgkm'd+barrier'd in iter kt-1 before
// STAGE(kt); every wave's vmcnt precedes barA before any READF.  obf: f32/bf16 C.
__global__ __launch_bounds__(512, 1) void k_gemm256(
        const unsigned short* __restrict__ A, long lda, long sA,
        const unsigned short* __restrict__ Bt, long ldb, long sB,
        void* __restrict__ Cc, long ldc, long sC, int K, int nbx, int nby, int obf) {
    __shared__ __align__(16) unsigned short As[2][256 * 64];   // 2 x 32KB
    __shared__ __align__(16) unsigned short Bs[2][256 * 64];   // 2 x 32KB
    int tid = threadIdx.x;
    int lane = tid & 63, w = tid >> 6;
    int wy = w >> 2, wx = w & 3;                            // 2 x 4 waves -> 128x64 per wave

    int nwg = gridDim.x;
    int cpx = nwg >> 3;
    int logical = (blockIdx.x & 7) * cpx + (blockIdx.x >> 3);
    int tpb = nbx * nby;
    int b = logical / tpb;
    int tile = logical % tpb;
    int i0 = (tile / nbx) * 256;
    int j0 = (tile % nbx) * 256;

    const unsigned short* Ab = A + (size_t)b * sA + (size_t)i0 * lda;
    const unsigned short* Bb = Bt + (size_t)b * sB + (size_t)j0 * ldb;

    auto STAGE = [&](int kt, int d) {
        int kof = kt << 6;
#pragma unroll
        for (int e = 0; e < 4; ++e) {
            int chunk = e * 512 + tid;
            int row = chunk >> 3, slot = chunk & 7;
            int gslot = slot ^ (row & 7);                   // inverse swizzle on source
            gload_lds16(Ab + (size_t)row * lda + kof + gslot * 8, &As[d][chunk * 8]);
        }
#pragma unroll
        for (int e = 0; e < 4; ++e) {
            int chunk = e * 512 + tid;
            int row = chunk >> 3, slot = chunk & 7;
            int gslot = slot ^ (row & 7);
            gload_lds16(Bb + (size_t)row * ldb + kof + gslot * 8, &Bs[d][chunk * 8]);
        }
    };

    struct Frag { short8 a0[8]; short8 b0[4]; short8 a1[8]; short8 b1[4]; };
    auto RD = [&](Frag& f, const unsigned short* Asb, const unsigned short* Bsb)
            __attribute__((always_inline)) {
#pragma unroll
        for (int mi = 0; mi < 8; ++mi) {
            int r = wy * 128 + mi * 16 + (lane & 15);
            int slot = (lane >> 4) ^ (r & 7);
            f.a0[mi] = *(const short8*)&Asb[r * 64 + slot * 8];
        }
#pragma unroll
        for (int ni = 0; ni < 4; ++ni) {
            int r = wx * 64 + ni * 16 + (lane & 15);
            int slot = (lane >> 4) ^ (r & 7);
            f.b0[ni] = *(const short8*)&Bsb[r * 64 + slot * 8];
        }
#pragma unroll
        for (int mi = 0; mi < 8; ++mi) {
            int r = wy * 128 + mi * 16 + (lane & 15);
            int slot = (4 + (lane >> 4)) ^ (r & 7);
            f.a1[mi] = *(const short8*)&Asb[r * 64 + slot * 8];
        }
#pragma unroll
        for (int ni = 0; ni < 4; ++ni) {
            int r = wx * 64 + ni * 16 + (lane & 15);
            int slot = (4 + (lane >> 4)) ^ (r & 7);
            f.b1[ni] = *(const short8*)&Bsb[r * 64 + slot * 8];
        }
    };

    f32x4 acc[8][4];
#pragma unroll
    for (int mi = 0; mi < 8; ++mi)
#pragma unroll
        for (int ni = 0; ni < 4; ++ni) acc[mi][ni] = (f32x4){0.f, 0.f, 0.f, 0.f};

    auto MFMA64 = [&](Frag& f) __attribute__((always_inline)) {
        __builtin_amdgcn_s_setprio(1);
#pragma unroll
        for (int mi = 0; mi < 8; ++mi)
#pragma unroll
            for (int ni = 0; ni < 4; ++ni)
                acc[mi][ni] = __builtin_amdgcn_mfma_f32_16x16x32_bf16(
                    f.a0[mi], f.b0[ni], acc[mi][ni], 0, 0, 0);
#pragma unroll
        for (int mi = 0; mi < 8; ++mi)
#pragma unroll
            for (int ni = 0; ni < 4; ++ni)
                acc[mi][ni] = __builtin_amdgcn_mfma_f32_16x16x32_bf16(
                    f.a1[mi], f.b1[ni], acc[mi][ni], 0, 0, 0);
        __builtin_amdgcn_s_setprio(0);
    };

    int nt = K >> 6;                                        // 16 or 48 (even, >= 2)
    int cur = 0;
    Frag fA, fB;

    STAGE(0, 0);
    STAGE(1, 1);
    asm volatile("s_waitcnt vmcnt(8)" ::: "memory");        // tile 0 resident
    __builtin_amdgcn_sched_barrier(0);
    __builtin_amdgcn_s_barrier();                           // barA (prologue)
    __builtin_amdgcn_sched_barrier(0);
    RD(fA, As[0], Bs[0]);
    asm volatile("s_waitcnt lgkmcnt(0)" ::: "memory");      // fA complete
    __builtin_amdgcn_sched_barrier(0);
    __builtin_amdgcn_s_barrier();                           // barB (prologue): reads done
    __builtin_amdgcn_sched_barrier(0);

    auto ITER = [&](int kt, Frag& fc, Frag& fn) __attribute__((always_inline)) {
        bool stg = (kt + 2 < nt);
        bool nxt = (kt + 1 < nt);
        if (stg) STAGE(kt + 2, cur);                        // buf[cur] data lives in fc regs
        __builtin_amdgcn_sched_barrier(0);
        if (nxt) {
            if (stg) { asm volatile("s_waitcnt vmcnt(8)" ::: "memory"); }
            else     { asm volatile("s_waitcnt vmcnt(0)" ::: "memory"); }
            __builtin_amdgcn_sched_barrier(0);
            __builtin_amdgcn_s_barrier();                   // barA: tile kt+1 resident
            __builtin_amdgcn_sched_barrier(0);
            RD(fn, As[cur ^ 1], Bs[cur ^ 1]);               // reads overlap MFMA below
        }
        MFMA64(fc);
        if (nxt) {
            asm volatile("s_waitcnt lgkmcnt(0)" ::: "memory");  // my reads retired
            __builtin_amdgcn_sched_barrier(0);
            __builtin_amdgcn_s_barrier();                   // barB: all reads before next STAGE
            __builtin_amdgcn_sched_barrier(0);
            cur ^= 1;
        }
    };

    for (int kt = 0; kt < nt; kt += 2) {
        ITER(kt, fA, fB);
        ITER(kt + 1, fB, fA);
    }

    if (obf) {
        unsigned short* Cb = (unsigned short*)Cc + (size_t)b * sC;
#pragma unroll
        for (int mi = 0; mi < 8; ++mi) {
#pragma unroll
            for (int r = 0; r < 4; ++r) {
                int i = i0 + wy * 128 + mi * 16 + (lane >> 4) * 4 + r;
                unsigned short* cp = Cb + (size_t)i * ldc + j0 + wx * 64 + (lane & 15);
#pragma unroll
                for (int ni = 0; ni < 4; ++ni) cp[ni * 16] = f2b(acc[mi][ni][r]);
            }
        }
    } else {
        float* Cb = (float*)Cc + (size_t)b * sC;
#pragma unroll
        for (int mi = 0; mi < 8; ++mi) {
#pragma unroll
            for (int r = 0; r < 4; ++r) {
                int i = i0 + wy * 128 + mi * 16 + (lane >> 4) * 4 + r;
                float* cp = Cb + (size_t)i * ldc + j0 + wx * 64 + (lane & 15);
#pragma unroll
                for (int ni = 0; ni < 4; ++ni) cp[ni * 16] = acc[mi][ni][r];
            }
        }
    }
}

// ---------------- fused epilogue via MFMA; sbf selects bf16/f32 gcn input ----------------
__global__ __launch_bounds__(256) void k_final(const float* __restrict__ x,
        const void* __restrict__ sgin, int sbf, const unsigned short* __restrict__ Wcat,
        const float* __restrict__ tc_b, const float* __restrict__ rc_b,
        const float* __restrict__ ln_g, const float* __restrict__ ln_b,
        float* __restrict__ out) {
    int b = blockIdx.y;
    int n0 = blockIdx.x * 4;
    int tid = threadIdx.x;
    int lane = tid & 63, wv = tid >> 6;

    __shared__ __align__(16) char smem[25600];
    unsigned short* sgb = (unsigned short*)smem;            // [4][26][64]
    unsigned short* xb  = (unsigned short*)(smem + 13312);  // [4][24][64]
    float* Cl = (float*)smem;                               // [96][66] (after reuse barrier)
    __shared__ float tbs[64], gs[64], bbs[64];
    __shared__ float mus[96], rss[96];

    if (tid < 64) {
        tbs[tid] = tc_b[tid] + rc_b[tid];
        gs[tid] = ln_g[tid];
        bbs[tid] = ln_b[tid];
    }
    for (int e = tid; e < 512; e += 256) {
        int nl = e >> 7, r = (e >> 6) & 1, c = e & 63;
        int tt = r ? 25 : 0;
        sgb[(nl * 26 + tt) * 64 + (((c >> 3) ^ (tt & 7)) << 3) + (c & 7)] = 0;
    }
    size_t base = ((size_t)b * N_ + n0) * CT_;
    const float4* xg4 = (const float4*)(x + base);
#pragma unroll
    for (int i = 0; i < 6; ++i) {                       // x staging (f32)
        int e4 = i * 256 + tid;
        float4 xv4 = xg4[e4];
        int e = e4 * 4;
        int nl = e / CT_;
        int rem = e - nl * CT_;
        int c = rem / 24;
        int tl = rem - c * 24;
        float xv[4] = {xv4.x, xv4.y, xv4.z, xv4.w};
#pragma unroll
        for (int j = 0; j < 4; ++j) {
            int tj = tl + j;
            xb[(nl * 24 + tj) * 64 + (((c >> 3) ^ (tj & 7)) << 3) + (c & 7)] = f2b(xv[j]);
        }
    }
    if (sbf) {                                          // gcn staging (bf16 input)
        const uint4* sg8 = (const uint4*)((const unsigned short*)sgin + base);
#pragma unroll
        for (int i = 0; i < 3; ++i) {
            int e8 = i * 256 + tid;
            uint4 v = sg8[e8];
            const unsigned short* sp = (const unsigned short*)&v;
            int e = e8 * 8;
            int nl = e / CT_;
            int rem = e - nl * CT_;
            int c = rem / 24;
            int tl = rem - c * 24;                       // tl in {0,8,16}
#pragma unroll
            for (int j = 0; j < 8; ++j) {
                int tt = tl + j + 1;
                unsigned short sb = sp[j];
                sgb[(nl * 26 + tt) * 64 + (((c >> 3) ^ (tt & 7)) << 3) + (c & 7)] =
                    (sb & 0x8000u) ? (unsigned short)0 : sb;   // relu on bf16 bits
            }
        }
    } else {                                            // gcn staging (f32 input)
        const float4* sg4 = (const float4*)((const float*)sgin + base);
#pragma unroll
        for (int i = 0; i < 6; ++i) {
            int e4 = i * 256 + tid;
            float4 sv4 = sg4[e4];
            int e = e4 * 4;
            int nl = e / CT_;
            int rem = e - nl * CT_;
            int c = rem / 24;
            int tl = rem - c * 24;
            float sv[4] = {sv4.x, sv4.y, sv4.z, sv4.w};
#pragma unroll
            for (int j = 0; j < 4; ++j) {
                int tt = tl + j + 1;
                sgb[(nl * 26 + tt) * 64 + (((c >> 3) ^ (tt & 7)) << 3) + (c & 7)] =
                    f2b(fmaxf(sv[j], 0.f));
            }
        }
    }

    int ft = wv * 16 + (lane & 15);
    int g4 = lane >> 4;
    short8 bfr[8];
#pragma unroll
    for (int ks = 0; ks < 8; ++ks)
        bfr[ks] = *(const short8*)&Wcat[ft * 256 + ks * 32 + g4 * 8];

    int rnl[6], rt[6];
#pragma unroll
    for (int mi = 0; mi < 6; ++mi) {
        int row = mi * 16 + (lane & 15);
        rnl[mi] = row / 24;
        rt[mi] = row - rnl[mi] * 24;
    }

    __syncthreads();

    f32x4 acc[6];
#pragma unroll
    for (int mi = 0; mi < 6; ++mi) acc[mi] = (f32x4){0.f, 0.f, 0.f, 0.f};
#pragma unroll
    for (int mi = 0; mi < 6; ++mi) {
        int nl = rnl[mi], t = rt[mi];
#pragma unroll
        for (int ks = 0; ks < 8; ++ks) {
            const int sel = ks >> 1;
            int slot = (ks & 1) * 4 + g4;
            short8 af;
            if (sel < 3) {
                int tt = t + sel;
                af = *(const short8*)&sgb[(nl * 26 + tt) * 64 + ((slot ^ (tt & 7)) << 3)];
            } else {
                af = *(const short8*)&xb[(nl * 24 + t) * 64 + ((slot ^ (t & 7)) << 3)];
            }
            acc[mi] = __builtin_amdgcn_mfma_f32_16x16x32_bf16(af, bfr[ks], acc[mi], 0, 0, 0);
        }
    }

    __syncthreads();
#pragma unroll
    for (int mi = 0; mi < 6; ++mi)
#pragma unroll
        for (int r = 0; r < 4; ++r)
            Cl[(mi * 16 + (lane >> 4) * 4 + r) * 66 + wv * 16 + (lane & 15)] = acc[mi][r];
    __syncthreads();

    if (tid < 96) {
        float s = 0.f, s2 = 0.f;
#pragma unroll
        for (int f = 0; f < 64; ++f) {
            float v = fmaxf(Cl[tid * 66 + f] + tbs[f], 0.f);
            s += v; s2 += v * v;
        }
        float mu = s * (1.f / 64.f);
        float var = s2 * (1.f / 64.f) - mu * mu;
        mus[tid] = mu;
        rss[tid] = rsqrtf(var + 1e-5f);
    }
    __syncthreads();

    float4* o4 = (float4*)(out + base);
#pragma unroll
    for (int i = 0; i < 6; ++i) {
        int e4 = i * 256 + tid;
        int e = e4 * 4;
        int nl = e / CT_;
        int rem = e - nl * CT_;
        int f = rem / 24;
        int t0v = rem - f * 24;
        float g = gs[f], bb2 = bbs[f], tb2 = tbs[f];
        float vals[4];
#pragma unroll
        for (int j = 0; j < 4; ++j) {
            int row = nl * 24 + t0v + j;
            float v = fmaxf(Cl[row * 66 + f] + tb2, 0.f);
            vals[j] = (v - mus[row]) * rss[row] * g + bb2;
        }
        float4 r;
        r.x = vals[0]; r.y = vals[1]; r.z = vals[2]; r.w = vals[3];
        o4[e4] = r;
    }
}

extern "C" void kernel_launch(void* const* d_in, const int* in_sizes, int n_in,
                              void* d_out, int out_size, void* d_ws, size_t ws_size,
                              hipStream_t stream) {
    const float* x    = (const float*)d_in[0];
    const float* cheb = (const float*)d_in[1];
    const float* U1   = (const float*)d_in[2];
    const float* U2   = (const float*)d_in[3];
    const float* U3   = (const float*)d_in[4];
    const float* b_e  = (const float*)d_in[5];
    const float* V_e  = (const float*)d_in[6];
    const float* W1   = (const float*)d_in[7];
    const float* W2   = (const float*)d_in[8];
    const float* W3   = (const float*)d_in[9];
    const float* b_s  = (const float*)d_in[10];
    const float* V_s  = (const float*)d_in[11];
    const float* Theta= (const float*)d_in[12];
    const float* tc_w = (const float*)d_in[13];
    const float* tc_b = (const float*)d_in[14];
    const float* rc_w = (const float*)d_in[15];
    const float* rc_b = (const float*)d_in[16];
    const float* ln_g = (const float*)d_in[17];
    const float* ln_b = (const float*)d_in[18];
    float* out = (float*)d_out;

    char* base = (char*)d_ws;
    size_t o = 0;
    auto alloc = [&](size_t bytes) { size_t r = o; o += (bytes + 255) & ~(size_t)255; return r; };
    float* lhs_t   = (float*)(base + alloc((size_t)B_ * T_ * N_ * 4));
    float* rhs_t   = (float*)(base + alloc((size_t)B_ * N_ * T_ * 4));
    float* Ebuf    = (float*)(base + alloc((size_t)B_ * T_ * T_ * 4));
    float* partial = (float*)(base + alloc((size_t)B_ * 32 * CT_ * 4));
    float* ptp     = (float*)(base + alloc((size_t)B_ * 8 * T_ * T_ * 4));
    float* lhs_t0  = (float*)(base + alloc((size_t)B_ * CT_ * 4));
    float* lhs_s   = (float*)(base + alloc((size_t)B_ * N_ * T_ * 4));
    float* rhs_s   = (float*)(base + alloc((size_t)B_ * T_ * N_ * 4));
    unsigned short* V_sb = (unsigned short*)(base + alloc((size_t)N_ * N_ * 2));
    unsigned short* Wcat = (unsigned short*)(base + alloc((size_t)F_ * 256 * 2));
    unsigned short* Thp  = (unsigned short*)(base + alloc((size_t)192 * 64 * 2));
    unsigned short* chb  = (unsigned short*)(base + alloc((size_t)3 * N_ * N_ * 2));
    float2* mstats = (float2*)(base + alloc((size_t)B_ * N_ * 8));
    size_t regA = alloc((size_t)B_ * N_ * KS_ * 2);   // xTt (bf16) -> chebSt (bf16)
    size_t regB = alloc((size_t)B_ * CT_ * KS_ * 2);  // sigA (bf16) -> yT (bf16)
    unsigned short* xTt    = (unsigned short*)(base + regA);
    unsigned short* chebSt = (unsigned short*)(base + regA);
    unsigned short* sigA   = (unsigned short*)(base + regB);
    unsigned short* yT     = (unsigned short*)(base + regB);
    unsigned short* Sb = (unsigned short*)out;   // bf16 S scores in d_out (dead before gcn)

    // optional aux region: bf16 gcn (halves stacked-GEMM write + k_final read).
    size_t gcn_bytes = (size_t)B_ * N_ * CT_ * 2;
    int use_aux = (ws_size >= o + gcn_bytes + 256) ? 1 : 0;
    unsigned short* gcnb = use_aux ? (unsigned short*)(base + alloc(gcn_bytes)) : nullptr;
    void* gcn_ptr = use_aux ? (void*)gcnb : (void*)out;
    const void* sgin = use_aux ? (const void*)gcnb : (const void*)out;

    dim3 b256(256);
    k_cvt_bf<<<dim3(N_ * N_ / 256), b256, 0, stream>>>(V_s, V_sb);
    k_cvt_bf<<<dim3(3 * N_ * N_ / 256), b256, 0, stream>>>(cheb, chb);
    k_wcat<<<dim3((F_ * 256 + 255) / 256), b256, 0, stream>>>(tc_w, rc_w, Wcat);
    k_thp<<<dim3((192 * 64 + 255) / 256), b256, 0, stream>>>(Theta, Thp);
    k_xreduce<<<dim3(N_ / 32, B_), b256, 0, stream>>>(x, U1, U3, rhs_t, partial);
    k_lhs_reduce<<<dim3((B_ * CT_ + 255) / 256), b256, 0, stream>>>(partial, lhs_t0);
    k_lhs_t<<<dim3((B_ * T_ * N_) / 256), b256, 0, stream>>>(lhs_t0, U2, lhs_t);
    k_prodt<<<dim3(8, B_), dim3(576), 0, stream>>>(lhs_t, rhs_t, ptp);
    k_temporal_E<<<dim3(B_), dim3(576), 0, stream>>>(ptp, b_e, V_e, Ebuf);
    k_tspatial<<<dim3(N_ / 4, B_), b256, 0, stream>>>(x, Ebuf, W1, W2, W3,
                                                      lhs_s, rhs_s, xTt);
    k_sig<<<dim3(N_ / 256, N_ / 64, B_), b256, 0, stream>>>(lhs_s, rhs_s, b_s, sigA);
    // S0 GEMM: M=1024, Ncols=1024, K=1024; bf16 C; nwg=512 (%8==0)
    k_gemm256<<<dim3(B_ * 4 * 4), dim3(512), 0, stream>>>(
        sigA, N_, (long)N_ * N_, V_sb, N_, 0, Sb, N_, (long)N_ * N_, N_, 4, 4, 1);
    k_smstats<<<dim3(N_ / 64, B_), b256, 0, stream>>>(Sb, mstats);
    k_yTmm<<<dim3(N_ / 128, B_ * T_), b256, 0, stream>>>(xTt, Thp, yT);        // sigA dead
    k_chebSt<<<dim3(N_ / 64, N_ / 64, B_), b256, 0, stream>>>(chb, Sb, mstats, chebSt); // xTt dead
    // stacked GEMM: M=1024, Ncols=1536, K=3072; nwg=768 (%8==0); bf16 C if aux fits
    k_gemm256<<<dim3(B_ * 4 * 6), dim3(512), 0, stream>>>(
        chebSt, KS_, (long)N_ * KS_, yT, KS_, (long)CT_ * KS_,
        gcn_ptr, CT_, (long)N_ * CT_, KS_, 6, 4, use_aux);                    // Sb dead
    k_final<<<dim3(N_ / 4, B_), b256, 0, stream>>>(x, sgin, use_aux, Wcat, tc_b, rc_b,
                                                   ln_g, ln_b, out);
}

// Round 16
// 993.975 us; speedup vs baseline: 3.1285x; 3.1285x over previous
//
#include <hip/hip_runtime.h>

typedef __attribute__((ext_vector_type(8))) short short8;   // 8 bf16 (4 VGPRs)
typedef __attribute__((ext_vector_type(4))) float f32x4;
typedef __attribute__((ext_vector_type(4))) unsigned short ushort4_;

constexpr int B_ = 32;
constexpr int N_ = 1024;
constexpr int C_ = 64;
constexpr int T_ = 24;
constexpr int F_ = 64;
constexpr int CT_ = C_ * T_;     // 1536
constexpr int KS_ = 3072;        // stacked K = 3*1024

__device__ __forceinline__ float sigmoidf_(float x) {
    return 1.0f / (1.0f + __expf(-x));
}
__device__ __forceinline__ unsigned short f2b(float f) {   // RNE f32->bf16
    union { float f; unsigned u; } v; v.f = f;
    unsigned r = v.u + 0x7FFFu + ((v.u >> 16) & 1u);
    return (unsigned short)(r >> 16);
}
__device__ __forceinline__ float b2f(unsigned short h) {
    union { unsigned u; float f; } v; v.u = ((unsigned)h) << 16; return v.f;
}
__device__ __forceinline__ void gload_lds16(const unsigned short* g, unsigned short* l) {
    __builtin_amdgcn_global_load_lds(
        (const __attribute__((address_space(1))) unsigned int*)g,
        (__attribute__((address_space(3))) unsigned int*)l, 16, 0, 0);
}

// ---------------- fused x reductions: rhs_t + U1-partial (one x read) ----------------
__global__ __launch_bounds__(256) void k_xreduce(const float* __restrict__ x,
        const float* __restrict__ U1, const float* __restrict__ U3,
        float* __restrict__ rhs_t, float* __restrict__ partial) {
    int b = blockIdx.y, g0 = blockIdx.x * 32;
    int tid = threadIdx.x;
    __shared__ float xr[8 * CT_];                        // 48 KB
    __shared__ float u3s[C_];
    if (tid < C_) u3s[tid] = U3[tid];
    float pacc[6] = {0, 0, 0, 0, 0, 0};
    for (int ph = 0; ph < 4; ++ph) {
        int n0 = g0 + ph * 8;
        __syncthreads();                                 // prev phase LDS reads done
        const float4* x4 = (const float4*)(x + ((size_t)(b * N_ + n0)) * CT_);
#pragma unroll
        for (int e = 0; e < 12; ++e) {
            int i4 = e * 256 + tid;
            float4 v = x4[i4];
            int i = i4 * 4;
            xr[i] = v.x; xr[i + 1] = v.y; xr[i + 2] = v.z; xr[i + 3] = v.w;
        }
        __syncthreads();
        if (tid < 192) {
            int n = tid / 24, t = tid % 24;
            const float* xn = xr + n * CT_ + t;
            float acc = 0.f;
#pragma unroll
            for (int c = 0; c < C_; ++c) acc += u3s[c] * xn[c * 24];
            rhs_t[((size_t)(b * N_ + n0 + n)) * T_ + t] = acc;
        }
#pragma unroll
        for (int n = 0; n < 8; ++n) {
            float u = U1[n0 + n];                        // uniform -> scalar
            const float* xn = xr + n * CT_;
#pragma unroll
            for (int e = 0; e < 6; ++e) pacc[e] += u * xn[tid + e * 256];
        }
    }
    float* pp = partial + ((size_t)(b * 32 + blockIdx.x)) * CT_;
#pragma unroll
    for (int e = 0; e < 6; ++e) pp[tid + e * 256] = pacc[e];
}

__global__ void k_lhs_reduce(const float* __restrict__ partial, float* __restrict__ lhs_t0) {
    int idx = blockIdx.x * 256 + threadIdx.x;
    if (idx >= B_ * CT_) return;
    int b = idx / CT_, flat = idx % CT_;
    float acc = 0.f;
#pragma unroll
    for (int ch = 0; ch < 32; ++ch) acc += partial[((size_t)(b * 32 + ch)) * CT_ + flat];
    lhs_t0[idx] = acc;
}

__global__ void k_lhs_t(const float* __restrict__ lhs_t0, const float* __restrict__ U2,
                        float* __restrict__ lhs_t) {
    int idx = blockIdx.x * 256 + threadIdx.x;
    if (idx >= B_ * T_ * N_) return;
    int n2 = idx % N_;
    int t = (idx / N_) % T_;
    int b = idx / (T_ * N_);
    const float* l0 = lhs_t0 + (size_t)b * CT_;
    float acc = 0.f;
#pragma unroll
    for (int c = 0; c < C_; ++c) acc += l0[c * T_ + t] * U2[c * N_ + n2];
    lhs_t[idx] = acc;
}

// prod_t partials: ptp[b][ch][i][u] = sum_{n in ch} lhs_t[b,i,n]*rhs_t[b,n,u]
__global__ __launch_bounds__(576) void k_prodt(const float* __restrict__ lhs_t,
        const float* __restrict__ rhs_t, float* __restrict__ ptp) {
    int b = blockIdx.y, ch = blockIdx.x;
    int tid = threadIdx.x;
    __shared__ float lt[24][128];
    __shared__ float rt[128][25];
    int n0 = ch * 128;
    for (int e = tid; e < 24 * 128; e += 576) {
        int i = e >> 7, nn = e & 127;
        lt[i][nn] = lhs_t[((size_t)b * T_ + i) * N_ + n0 + nn];
    }
    const float* rg = rhs_t + ((size_t)b * N_ + n0) * T_;
    for (int e = tid; e < 128 * 24; e += 576) {
        int nn = e / 24, t = e - nn * 24;
        rt[nn][t] = rg[e];
    }
    __syncthreads();
    int i = tid / 24, u = tid - (tid / 24) * 24;
    float acc = 0.f;
#pragma unroll 8
    for (int nn = 0; nn < 128; ++nn) acc += lt[i][nn] * rt[nn][u];
    ptp[(((size_t)b * 8 + ch) * 24 + i) * 24 + u] = acc;
}

__global__ void k_temporal_E(const float* __restrict__ ptp,
                             const float* __restrict__ b_e, const float* __restrict__ V_e,
                             float* __restrict__ E) {
    int b = blockIdx.x;
    int tid = threadIdx.x;                               // 576 threads
    int i = tid / T_, u = tid % T_;
    __shared__ float sig[T_][T_];
    __shared__ float e0s[T_][T_];
    __shared__ float mcol[T_], scol[T_];
    float acc = 0.f;
#pragma unroll
    for (int ch = 0; ch < 8; ++ch)
        acc += ptp[(((size_t)b * 8 + ch) * 24 + i) * 24 + u];
    sig[i][u] = sigmoidf_(acc + b_e[i * T_ + u]);
    __syncthreads();
    int j = u;
    float e0 = 0.f;
#pragma unroll
    for (int kk = 0; kk < T_; ++kk) e0 += sig[i][kk] * V_e[j * T_ + kk];
    e0s[i][j] = e0;
    __syncthreads();
    if (tid < T_) {
        float mx = -1e30f;
        for (int ii = 0; ii < T_; ++ii) mx = fmaxf(mx, e0s[ii][tid]);
        float s = 0.f;
        for (int ii = 0; ii < T_; ++ii) s += __expf(e0s[ii][tid] - mx);
        mcol[tid] = mx; scol[tid] = s;
    }
    __syncthreads();
    E[(size_t)b * T_ * T_ + i * T_ + j] = __expf(e0s[i][j] - mcol[j]) / scol[j];
}

// ---------------- fused: x_TAt (in-register) -> spatial prep + xTt emit ----------------
__global__ __launch_bounds__(256) void k_tspatial(const float* __restrict__ x,
        const float* __restrict__ E, const float* __restrict__ W1g,
        const float* __restrict__ W2, const float* __restrict__ W3g,
        float* __restrict__ lhs_s, float* __restrict__ rhs_s,
        unsigned short* __restrict__ xTt) {
    int b = blockIdx.y;
    int n0 = blockIdx.x * 4;
    int tid = threadIdx.x;
    __shared__ float Es[T_ * T_];
    __shared__ float W1s[T_];
    __shared__ float W2s[C_ * T_];
    __shared__ float xr[4][64][25];                      // staged x, then reused for w3*u
    __shared__ float l0s[4][64];
    for (int e = tid; e < T_ * T_; e += 256) Es[e] = E[(size_t)b * T_ * T_ + e];
    for (int e = tid; e < C_ * T_; e += 256) W2s[e] = W2[e];
    if (tid < T_) W1s[tid] = W1g[tid];
    size_t base = ((size_t)b * N_ + n0) * CT_;
    const float4* x4 = (const float4*)(x + base);
#pragma unroll
    for (int i = 0; i < 6; ++i) {
        int e4 = i * 256 + tid;
        float4 v = x4[e4];
        int e = e4 * 4;
        int nl = e / CT_; int rem = e - nl * CT_; int c = rem / 24; int tl = rem - c * 24;
        xr[nl][c][tl] = v.x; xr[nl][c][tl + 1] = v.y;
        xr[nl][c][tl + 2] = v.z; xr[nl][c][tl + 3] = v.w;
    }
    __syncthreads();
    int nl = tid >> 6, c = tid & 63;
    float xv[T_];
#pragma unroll
    for (int t = 0; t < T_; ++t) xv[t] = xr[nl][c][t];
    // emit xTt[b][t][n][c] bf16 from staged x (coalesced 128B chunks)
#pragma unroll
    for (int i = 0; i < 24; ++i) {
        int idx = i * 256 + tid;
        int cc = idx & 63, nn = (idx >> 6) & 3, t = idx >> 8;
        xTt[((size_t)(b * T_ + t) * N_ + n0 + nn) * 64 + cc] = f2b(xr[nn][cc][t]);
    }
    float w3 = W3g[c];
    float u[T_];
#pragma unroll
    for (int j = 0; j < T_; ++j) {
        float a = 0.f;
#pragma unroll
        for (int t = 0; t < T_; ++t) a += xv[t] * Es[t * T_ + j];
        u[j] = a;
    }
    float l0 = 0.f;
#pragma unroll
    for (int j = 0; j < T_; ++j) l0 += u[j] * W1s[j];
    __syncthreads();                                     // xTt-emit LDS reads done
#pragma unroll
    for (int j = 0; j < T_; ++j) xr[nl][c][j] = w3 * u[j];
    l0s[nl][c] = l0;
    __syncthreads();
    if (tid < 4 * T_) {
        int t = tid % T_, g = tid / T_;
        float racc = 0.f, lacc = 0.f;
        for (int cc = 0; cc < 64; ++cc) {
            racc += xr[g][cc][t];
            lacc += l0s[g][cc] * W2s[cc * T_ + t];
        }
        rhs_s[((size_t)b * T_ + t) * N_ + n0 + g] = racc;
        lhs_s[((size_t)(b * N_ + n0 + g)) * T_ + t] = lacc;
    }
}

// ---------------- converters / builders ----------------
__global__ void k_cvt_bf(const float* __restrict__ v, unsigned short* __restrict__ o) {
    int i = blockIdx.x * 256 + threadIdx.x;
    o[i] = f2b(v[i]);
}

// Wcat[ft][k], k = sel*64+c: sel 0..2 -> tc_w taps, sel 3 -> rc_w.  bf16 [64][256]
__global__ void k_wcat(const float* __restrict__ tc_w, const float* __restrict__ rc_w,
                       unsigned short* __restrict__ Wcat) {
    int i = blockIdx.x * 256 + threadIdx.x;              // over 64*256
    if (i >= F_ * 256) return;
    int ft = i >> 8, k = i & 255;
    int sel = k >> 6, c = k & 63;
    float v = (sel < 3) ? tc_w[(ft * C_ + c) * 3 + sel] : rc_w[ft * C_ + c];
    Wcat[i] = f2b(v);
}

// Thp[k*64+f][c] (bf16) = Theta[k][c][f]   -- A-operand for k_yTmm
__global__ void k_thp(const float* __restrict__ Theta, unsigned short* __restrict__ Thp) {
    int i = blockIdx.x * 256 + threadIdx.x;              // over 192*64
    if (i >= 192 * 64) return;
    int kf = i >> 6, c = i & 63;
    int k = kf >> 6, f = kf & 63;
    Thp[i] = f2b(Theta[((size_t)k * 64 + c) * 64 + f]);
}

// sigA[b][i][k] (bf16) = sigmoid(dot24(lhs_s[b,i,:], rhs_s[b,:,k]) + b_s[i,k])
__global__ __launch_bounds__(256) void k_sig(const float* __restrict__ lhs_s,
        const float* __restrict__ rhs_s, const float* __restrict__ b_s,
        unsigned short* __restrict__ sigA) {
    int b = blockIdx.z, i0 = blockIdx.y * 64, k0 = blockIdx.x * 256;
    int tid = threadIdx.x;
    __shared__ float lh[64 * T_];
    __shared__ float rh[T_][256];
    for (int e = tid; e < 64 * T_; e += 256) lh[e] = lhs_s[((size_t)b * N_ + i0) * T_ + e];
#pragma unroll
    for (int t = 0; t < T_; ++t) rh[t][tid] = rhs_s[((size_t)b * T_ + t) * N_ + k0 + tid];
    __syncthreads();
    int kg = k0 + tid;
    for (int ii = 0; ii < 64; ++ii) {
        float acc = b_s[(size_t)(i0 + ii) * N_ + kg];
#pragma unroll
        for (int t = 0; t < T_; ++t) acc += lh[ii * T_ + t] * rh[t][tid];
        sigA[((size_t)b * N_ + i0 + ii) * N_ + kg] = f2b(sigmoidf_(acc));
    }
}

// ---------------- yT via MFMA, coalesced stores through LDS C-tile ----------------
__global__ __launch_bounds__(256) void k_yTmm(const unsigned short* __restrict__ xTt,
        const unsigned short* __restrict__ Thp, unsigned short* __restrict__ yT) {
    int bt = blockIdx.y;
    int b = bt / T_, t = bt - b * T_;
    int m0 = blockIdx.x * 128;
    int tid = threadIdx.x;
    int lane = tid & 63, wv = tid >> 6;
    __shared__ __align__(16) char smem[50688];
    unsigned short* Asb = (unsigned short*)smem;             // [192*64] (live whole kernel)
    unsigned short* Bsb = (unsigned short*)(smem + 24576);   // [128*64]
    unsigned short* Cl  = (unsigned short*)(smem + 24576);   // [96][136] (after Bsb dead)
#pragma unroll
    for (int e = 0; e < 6; ++e) {                        // stage Thp (24KB)
        int chunk = e * 256 + tid;
        int row = chunk >> 3, slot = chunk & 7;
        int gslot = slot ^ (row & 7);
        gload_lds16(Thp + row * 64 + gslot * 8, &Asb[chunk * 8]);
    }
    const unsigned short* Bg = xTt + ((size_t)bt * N_ + m0) * 64;
#pragma unroll
    for (int e = 0; e < 4; ++e) {                        // stage B (16KB)
        int chunk = e * 256 + tid;
        int row = chunk >> 3, slot = chunk & 7;
        int gslot = slot ^ (row & 7);
        gload_lds16(Bg + (size_t)row * 64 + gslot * 8, &Bsb[chunk * 8]);
    }
    __syncthreads();                                     // drains vmcnt

    short8 bf[2][2];
#pragma unroll
    for (int ni = 0; ni < 2; ++ni)
#pragma unroll
        for (int kk = 0; kk < 2; ++kk) {
            int r = wv * 32 + ni * 16 + (lane & 15);
            int slot = (kk * 4 + (lane >> 4)) ^ (r & 7);
            bf[ni][kk] = *(const short8*)&Bsb[r * 64 + slot * 8];
        }
    f32x4 acc[12][2];
#pragma unroll
    for (int mi = 0; mi < 12; ++mi)
#pragma unroll
        for (int ni = 0; ni < 2; ++ni) acc[mi][ni] = (f32x4){0.f, 0.f, 0.f, 0.f};
#pragma unroll
    for (int mi = 0; mi < 12; ++mi) {
        short8 af[2];
#pragma unroll
        for (int kk = 0; kk < 2; ++kk) {
            int r = mi * 16 + (lane & 15);
            int slot = (kk * 4 + (lane >> 4)) ^ (r & 7);
            af[kk] = *(const short8*)&Asb[r * 64 + slot * 8];
        }
#pragma unroll
        for (int kk = 0; kk < 2; ++kk)
#pragma unroll
            for (int ni = 0; ni < 2; ++ni)
                acc[mi][ni] = __builtin_amdgcn_mfma_f32_16x16x32_bf16(
                    af[kk], bf[ni][kk], acc[mi][ni], 0, 0, 0);
    }
#pragma unroll
    for (int h = 0; h < 2; ++h) {
        __syncthreads();
#pragma unroll
        for (int mi2 = 0; mi2 < 6; ++mi2) {
            int mi = h * 6 + mi2;
#pragma unroll
            for (int r = 0; r < 4; ++r) {
                int row = mi2 * 16 + (lane >> 4) * 4 + r;
#pragma unroll
                for (int ni = 0; ni < 2; ++ni)
                    Cl[row * 136 + wv * 32 + ni * 16 + (lane & 15)] = f2b(acc[mi][ni][r]);
            }
        }
        __syncthreads();
#pragma unroll
        for (int e = 0; e < 6; ++e) {
            int idx = e * 256 + tid;
            int row = idx >> 4, seg = idx & 15;
            int kf = h * 96 + row;
            int k = kf >> 6, f = kf & 63;
            uint4 v = *(const uint4*)&Cl[row * 136 + seg * 8];
            *(uint4*)&yT[((size_t)b * CT_ + f * T_ + t) * KS_ + k * N_ + m0 + seg * 8] = v;
        }
    }
}

// online softmax stats over axis m of S[b,m,i] (bf16): mst[b*N+i] = (max, 1/sum)
__global__ void k_smstats(const unsigned short* __restrict__ S, float2* __restrict__ mst) {
    int b = blockIdx.y;
    int jj = threadIdx.x % 64;
    int ig = threadIdx.x / 64;
    int j = blockIdx.x * 64 + jj;
    __shared__ float rm[4][64], rs[4][64];
    float m = -1e30f, s = 0.f;
    for (int i = ig; i < N_; i += 4) {
        float v = b2f(S[((size_t)b * N_ + i) * N_ + j]);
        float mn = fmaxf(m, v);
        s = s * __expf(m - mn) + __expf(v - mn);
        m = mn;
    }
    rm[ig][jj] = m; rs[ig][jj] = s;
    __syncthreads();
    if (ig == 0) {
        float M = rm[0][jj], SS = rs[0][jj];
#pragma unroll
        for (int g = 1; g < 4; ++g) {
            float mg = rm[g][jj];
            float mn = fmaxf(M, mg);
            SS = SS * __expf(M - mn) + rs[g][jj] * __expf(mg - mn);
            M = mn;
        }
        mst[(size_t)b * N_ + j] = make_float2(M, 1.f / SS);
    }
}

// chebSt[b][i][k*1024+m] (bf16) = chb[k][m][i] * softmax(S)[b][m][i]  (bf16 reads)
__global__ __launch_bounds__(256) void k_chebSt(const unsigned short* __restrict__ chb,
        const unsigned short* __restrict__ S, const float2* __restrict__ mst,
        unsigned short* __restrict__ cs) {
    int b = blockIdx.z, i0 = blockIdx.y * 64, m0 = blockIdx.x * 64;
    int tid = threadIdx.x;
    __shared__ float st[64][65];
    __shared__ float cb[64][65];
    __shared__ float2 sst[64];
    if (tid < 64) sst[tid] = mst[(size_t)b * N_ + i0 + tid];
#pragma unroll
    for (int e = 0; e < 4; ++e) {
        int idx4 = e * 256 + tid;
        int mm = idx4 >> 4, ii0 = (idx4 & 15) * 4;
        ushort4_ v = *(const ushort4_*)&S[((size_t)b * N_ + m0 + mm) * N_ + i0 + ii0];
        st[mm][ii0] = b2f(v.x); st[mm][ii0 + 1] = b2f(v.y);
        st[mm][ii0 + 2] = b2f(v.z); st[mm][ii0 + 3] = b2f(v.w);
    }
    for (int k = 0; k < 3; ++k) {
        __syncthreads();
#pragma unroll
        for (int e = 0; e < 4; ++e) {
            int idx4 = e * 256 + tid;
            int mm = idx4 >> 4, ii0 = (idx4 & 15) * 4;
            ushort4_ v = *(const ushort4_*)&chb[((size_t)k * N_ + m0 + mm) * N_ + i0 + ii0];
            cb[mm][ii0] = b2f(v.x); cb[mm][ii0 + 1] = b2f(v.y);
            cb[mm][ii0 + 2] = b2f(v.z); cb[mm][ii0 + 3] = b2f(v.w);
        }
        __syncthreads();
#pragma unroll
        for (int e = 0; e < 16; ++e) {
            int idx = e * 256 + tid; int mm = idx & 63, ii = idx >> 6;
            float sm = __expf(st[mm][ii] - sst[ii].x) * sst[ii].y;
            cs[((size_t)b * N_ + i0 + ii) * KS_ + k * N_ + m0 + mm] =
                f2b(sm * cb[mm][ii]);
        }
    }
}

// ---------------- 256x256-tile MFMA GEMM, hybrid counted-vmcnt pipeline (R14) ----------
// obf: 0 -> f32 C, 1 -> bf16 C (ldc in elements either way)
__global__ __launch_bounds__(512, 2) void k_gemm256(
        const unsigned short* __restrict__ A, long lda, long sA,
        const unsigned short* __restrict__ Bt, long ldb, long sB,
        void* __restrict__ Cc, long ldc, long sC, int K, int nbx, int nby, int obf) {
    __shared__ __align__(16) unsigned short As[2][256 * 64];   // 2 x 32KB
    __shared__ __align__(16) unsigned short Bs[2][256 * 64];   // 2 x 32KB
    int tid = threadIdx.x;
    int lane = tid & 63, w = tid >> 6;
    int wy = w >> 2, wx = w & 3;                            // 2 x 4 waves -> 128x64 per wave

    int nwg = gridDim.x;
    int cpx = nwg >> 3;
    int logical = (blockIdx.x & 7) * cpx + (blockIdx.x >> 3);
    int tpb = nbx * nby;
    int b = logical / tpb;
    int tile = logical % tpb;
    int i0 = (tile / nbx) * 256;
    int j0 = (tile % nbx) * 256;

    const unsigned short* Ab = A + (size_t)b * sA + (size_t)i0 * lda;
    const unsigned short* Bb = Bt + (size_t)b * sB + (size_t)j0 * ldb;

    auto STAGE = [&](int kt, int d) {
        int kof = kt << 6;
#pragma unroll
        for (int e = 0; e < 4; ++e) {
            int chunk = e * 512 + tid;
            int row = chunk >> 3, slot = chunk & 7;
            int gslot = slot ^ (row & 7);                   // inverse swizzle on source
            gload_lds16(Ab + (size_t)row * lda + kof + gslot * 8, &As[d][chunk * 8]);
        }
#pragma unroll
        for (int e = 0; e < 4; ++e) {
            int chunk = e * 512 + tid;
            int row = chunk >> 3, slot = chunk & 7;
            int gslot = slot ^ (row & 7);
            gload_lds16(Bb + (size_t)row * ldb + kof + gslot * 8, &Bs[d][chunk * 8]);
        }
    };
    auto READF = [&](short8* af, short8* bfv,
                     const unsigned short* Asb, const unsigned short* Bsb, int kkb) {
#pragma unroll
        for (int mi = 0; mi < 8; ++mi) {
            int r = wy * 128 + mi * 16 + (lane & 15);
            int slot = (kkb + (lane >> 4)) ^ (r & 7);
            af[mi] = *(const short8*)&Asb[r * 64 + slot * 8];
        }
#pragma unroll
        for (int ni = 0; ni < 4; ++ni) {
            int r = wx * 64 + ni * 16 + (lane & 15);
            int slot = (kkb + (lane >> 4)) ^ (r & 7);
            bfv[ni] = *(const short8*)&Bsb[r * 64 + slot * 8];
        }
    };

    f32x4 acc[8][4];
#pragma unroll
    for (int mi = 0; mi < 8; ++mi)
#pragma unroll
        for (int ni = 0; ni < 4; ++ni) acc[mi][ni] = (f32x4){0.f, 0.f, 0.f, 0.f};

    int nt = K >> 6;
    STAGE(0, 0);
    STAGE(1, 1);
    asm volatile("s_waitcnt vmcnt(8)" ::: "memory");        // K-tile 0 resident
    __builtin_amdgcn_s_barrier();
    __builtin_amdgcn_sched_barrier(0);

    short8 a0[8], b0[4], a1[8], b1[4];
    READF(a0, b0, As[0], Bs[0], 0);                         // kk0 of tile 0

    for (int kt = 0; kt < nt; ++kt) {
        int cur = kt & 1;
        READF(a1, b1, As[cur], Bs[cur], 4);                 // kk1 of this tile
        __builtin_amdgcn_s_setprio(1);
#pragma unroll
        for (int mi = 0; mi < 8; ++mi)
#pragma unroll
            for (int ni = 0; ni < 4; ++ni)
                acc[mi][ni] = __builtin_amdgcn_mfma_f32_16x16x32_bf16(
                    a0[mi], b0[ni], acc[mi][ni], 0, 0, 0);
        __builtin_amdgcn_s_setprio(0);
        asm volatile("s_waitcnt lgkmcnt(0)" ::: "memory");  // my reads of buf[cur] done
        __builtin_amdgcn_sched_barrier(0);
        __builtin_amdgcn_s_barrier();                       // all waves done with buf[cur]
        __builtin_amdgcn_sched_barrier(0);
        if (kt + 2 < nt) STAGE(kt + 2, cur);                // overwrite freed buffer
        __builtin_amdgcn_sched_barrier(0);
        __builtin_amdgcn_s_setprio(1);
#pragma unroll
        for (int mi = 0; mi < 8; ++mi)
#pragma unroll
            for (int ni = 0; ni < 4; ++ni)
                acc[mi][ni] = __builtin_amdgcn_mfma_f32_16x16x32_bf16(
                    a1[mi], b1[ni], acc[mi][ni], 0, 0, 0);
        __builtin_amdgcn_s_setprio(0);
        if (kt + 2 < nt) {
            asm volatile("s_waitcnt vmcnt(8)" ::: "memory"); // kt+1 retired, kt+2 in flight
        } else {
            asm volatile("s_waitcnt vmcnt(0)" ::: "memory"); // tail: drain (race-safe)
        }
        __builtin_amdgcn_s_barrier();                       // buf[cur^1] ready for all waves
        __builtin_amdgcn_sched_barrier(0);
        if (kt + 1 < nt)
            READF(a0, b0, As[cur ^ 1], Bs[cur ^ 1], 0);     // kk0 of next tile
    }

    if (obf) {
        unsigned short* Cb = (unsigned short*)Cc + (size_t)b * sC;
#pragma unroll
        for (int mi = 0; mi < 8; ++mi) {
#pragma unroll
            for (int r = 0; r < 4; ++r) {
                int i = i0 + wy * 128 + mi * 16 + (lane >> 4) * 4 + r;
                unsigned short* cp = Cb + (size_t)i * ldc + j0 + wx * 64 + (lane & 15);
#pragma unroll
                for (int ni = 0; ni < 4; ++ni) cp[ni * 16] = f2b(acc[mi][ni][r]);
            }
        }
    } else {
        float* Cb = (float*)Cc + (size_t)b * sC;
#pragma unroll
        for (int mi = 0; mi < 8; ++mi) {
#pragma unroll
            for (int r = 0; r < 4; ++r) {
                int i = i0 + wy * 128 + mi * 16 + (lane >> 4) * 4 + r;
                float* cp = Cb + (size_t)i * ldc + j0 + wx * 64 + (lane & 15);
#pragma unroll
                for (int ni = 0; ni < 4; ++ni) cp[ni * 16] = acc[mi][ni][r];
            }
        }
    }
}

// ---------------- fused epilogue via MFMA; sbf selects bf16/f32 gcn input ----------------
__global__ __launch_bounds__(256) void k_final(const float* __restrict__ x,
        const void* __restrict__ sgin, int sbf, const unsigned short* __restrict__ Wcat,
        const float* __restrict__ tc_b, const float* __restrict__ rc_b,
        const float* __restrict__ ln_g, const float* __restrict__ ln_b,
        float* __restrict__ out) {
    int b = blockIdx.y;
    int n0 = blockIdx.x * 4;
    int tid = threadIdx.x;
    int lane = tid & 63, wv = tid >> 6;

    __shared__ __align__(16) char smem[25600];
    unsigned short* sgb = (unsigned short*)smem;            // [4][26][64]
    unsigned short* xb  = (unsigned short*)(smem + 13312);  // [4][24][64]
    float* Cl = (float*)smem;                               // [96][66] (after reuse barrier)
    __shared__ float tbs[64], gs[64], bbs[64];
    __shared__ float mus[96], rss[96];

    if (tid < 64) {
        tbs[tid] = tc_b[tid] + rc_b[tid];
        gs[tid] = ln_g[tid];
        bbs[tid] = ln_b[tid];
    }
    for (int e = tid; e < 512; e += 256) {
        int nl = e >> 7, r = (e >> 6) & 1, c = e & 63;
        int tt = r ? 25 : 0;
        sgb[(nl * 26 + tt) * 64 + (((c >> 3) ^ (tt & 7)) << 3) + (c & 7)] = 0;
    }
    size_t base = ((size_t)b * N_ + n0) * CT_;
    const float4* xg4 = (const float4*)(x + base);
#pragma unroll
    for (int i = 0; i < 6; ++i) {                       // x staging (f32)
        int e4 = i * 256 + tid;
        float4 xv4 = xg4[e4];
        int e = e4 * 4;
        int nl = e / CT_;
        int rem = e - nl * CT_;
        int c = rem / 24;
        int tl = rem - c * 24;
        float xv[4] = {xv4.x, xv4.y, xv4.z, xv4.w};
#pragma unroll
        for (int j = 0; j < 4; ++j) {
            int tj = tl + j;
            xb[(nl * 24 + tj) * 64 + (((c >> 3) ^ (tj & 7)) << 3) + (c & 7)] = f2b(xv[j]);
        }
    }
    if (sbf) {                                          // gcn staging (bf16 input)
        const uint4* sg8 = (const uint4*)((const unsigned short*)sgin + base);
#pragma unroll
        for (int i = 0; i < 3; ++i) {
            int e8 = i * 256 + tid;
            uint4 v = sg8[e8];
            const unsigned short* sp = (const unsigned short*)&v;
            int e = e8 * 8;
            int nl = e / CT_;
            int rem = e - nl * CT_;
            int c = rem / 24;
            int tl = rem - c * 24;                       // tl in {0,8,16}
#pragma unroll
            for (int j = 0; j < 8; ++j) {
                int tt = tl + j + 1;
                unsigned short sb = sp[j];
                sgb[(nl * 26 + tt) * 64 + (((c >> 3) ^ (tt & 7)) << 3) + (c & 7)] =
                    (sb & 0x8000u) ? (unsigned short)0 : sb;   // relu on bf16 bits
            }
        }
    } else {                                            // gcn staging (f32 input)
        const float4* sg4 = (const float4*)((const float*)sgin + base);
#pragma unroll
        for (int i = 0; i < 6; ++i) {
            int e4 = i * 256 + tid;
            float4 sv4 = sg4[e4];
            int e = e4 * 4;
            int nl = e / CT_;
            int rem = e - nl * CT_;
            int c = rem / 24;
            int tl = rem - c * 24;
            float sv[4] = {sv4.x, sv4.y, sv4.z, sv4.w};
#pragma unroll
            for (int j = 0; j < 4; ++j) {
                int tt = tl + j + 1;
                sgb[(nl * 26 + tt) * 64 + (((c >> 3) ^ (tt & 7)) << 3) + (c & 7)] =
                    f2b(fmaxf(sv[j], 0.f));
            }
        }
    }

    int ft = wv * 16 + (lane & 15);
    int g4 = lane >> 4;
    short8 bfr[8];
#pragma unroll
    for (int ks = 0; ks < 8; ++ks)
        bfr[ks] = *(const short8*)&Wcat[ft * 256 + ks * 32 + g4 * 8];

    int rnl[6], rt[6];
#pragma unroll
    for (int mi = 0; mi < 6; ++mi) {
        int row = mi * 16 + (lane & 15);
        rnl[mi] = row / 24;
        rt[mi] = row - rnl[mi] * 24;
    }

    __syncthreads();

    f32x4 acc[6];
#pragma unroll
    for (int mi = 0; mi < 6; ++mi) acc[mi] = (f32x4){0.f, 0.f, 0.f, 0.f};
#pragma unroll
    for (int mi = 0; mi < 6; ++mi) {
        int nl = rnl[mi], t = rt[mi];
#pragma unroll
        for (int ks = 0; ks < 8; ++ks) {
            const int sel = ks >> 1;
            int slot = (ks & 1) * 4 + g4;
            short8 af;
            if (sel < 3) {
                int tt = t + sel;
                af = *(const short8*)&sgb[(nl * 26 + tt) * 64 + ((slot ^ (tt & 7)) << 3)];
            } else {
                af = *(const short8*)&xb[(nl * 24 + t) * 64 + ((slot ^ (t & 7)) << 3)];
            }
            acc[mi] = __builtin_amdgcn_mfma_f32_16x16x32_bf16(af, bfr[ks], acc[mi], 0, 0, 0);
        }
    }

    __syncthreads();
#pragma unroll
    for (int mi = 0; mi < 6; ++mi)
#pragma unroll
        for (int r = 0; r < 4; ++r)
            Cl[(mi * 16 + (lane >> 4) * 4 + r) * 66 + wv * 16 + (lane & 15)] = acc[mi][r];
    __syncthreads();

    if (tid < 96) {
        float s = 0.f, s2 = 0.f;
#pragma unroll
        for (int f = 0; f < 64; ++f) {
            float v = fmaxf(Cl[tid * 66 + f] + tbs[f], 0.f);
            s += v; s2 += v * v;
        }
        float mu = s * (1.f / 64.f);
        float var = s2 * (1.f / 64.f) - mu * mu;
        mus[tid] = mu;
        rss[tid] = rsqrtf(var + 1e-5f);
    }
    __syncthreads();

    float4* o4 = (float4*)(out + base);
#pragma unroll
    for (int i = 0; i < 6; ++i) {
        int e4 = i * 256 + tid;
        int e = e4 * 4;
        int nl = e / CT_;
        int rem = e - nl * CT_;
        int f = rem / 24;
        int t0v = rem - f * 24;
        float g = gs[f], bb2 = bbs[f], tb2 = tbs[f];
        float vals[4];
#pragma unroll
        for (int j = 0; j < 4; ++j) {
            int row = nl * 24 + t0v + j;
            float v = fmaxf(Cl[row * 66 + f] + tb2, 0.f);
            vals[j] = (v - mus[row]) * rss[row] * g + bb2;
        }
        float4 r;
        r.x = vals[0]; r.y = vals[1]; r.z = vals[2]; r.w = vals[3];
        o4[e4] = r;
    }
}

extern "C" void kernel_launch(void* const* d_in, const int* in_sizes, int n_in,
                              void* d_out, int out_size, void* d_ws, size_t ws_size,
                              hipStream_t stream) {
    const float* x    = (const float*)d_in[0];
    const float* cheb = (const float*)d_in[1];
    const float* U1   = (const float*)d_in[2];
    const float* U2   = (const float*)d_in[3];
    const float* U3   = (const float*)d_in[4];
    const float* b_e  = (const float*)d_in[5];
    const float* V_e  = (const float*)d_in[6];
    const float* W1   = (const float*)d_in[7];
    const float* W2   = (const float*)d_in[8];
    const float* W3   = (const float*)d_in[9];
    const float* b_s  = (const float*)d_in[10];
    const float* V_s  = (const float*)d_in[11];
    const float* Theta= (const float*)d_in[12];
    const float* tc_w = (const float*)d_in[13];
    const float* tc_b = (const float*)d_in[14];
    const float* rc_w = (const float*)d_in[15];
    const float* rc_b = (const float*)d_in[16];
    const float* ln_g = (const float*)d_in[17];
    const float* ln_b = (const float*)d_in[18];
    float* out = (float*)d_out;

    char* base = (char*)d_ws;
    size_t o = 0;
    auto alloc = [&](size_t bytes) { size_t r = o; o += (bytes + 255) & ~(size_t)255; return r; };
    float* lhs_t   = (float*)(base + alloc((size_t)B_ * T_ * N_ * 4));
    float* rhs_t   = (float*)(base + alloc((size_t)B_ * N_ * T_ * 4));
    float* Ebuf    = (float*)(base + alloc((size_t)B_ * T_ * T_ * 4));
    float* partial = (float*)(base + alloc((size_t)B_ * 32 * CT_ * 4));
    float* ptp     = (float*)(base + alloc((size_t)B_ * 8 * T_ * T_ * 4));
    float* lhs_t0  = (float*)(base + alloc((size_t)B_ * CT_ * 4));
    float* lhs_s   = (float*)(base + alloc((size_t)B_ * N_ * T_ * 4));
    float* rhs_s   = (float*)(base + alloc((size_t)B_ * T_ * N_ * 4));
    unsigned short* V_sb = (unsigned short*)(base + alloc((size_t)N_ * N_ * 2));
    unsigned short* Wcat = (unsigned short*)(base + alloc((size_t)F_ * 256 * 2));
    unsigned short* Thp  = (unsigned short*)(base + alloc((size_t)192 * 64 * 2));
    unsigned short* chb  = (unsigned short*)(base + alloc((size_t)3 * N_ * N_ * 2));
    float2* mstats = (float2*)(base + alloc((size_t)B_ * N_ * 8));
    size_t regA = alloc((size_t)B_ * N_ * KS_ * 2);   // xTt (bf16) -> chebSt (bf16)
    size_t regB = alloc((size_t)B_ * CT_ * KS_ * 2);  // sigA (bf16) -> yT (bf16)
    unsigned short* xTt    = (unsigned short*)(base + regA);
    unsigned short* chebSt = (unsigned short*)(base + regA);
    unsigned short* sigA   = (unsigned short*)(base + regB);
    unsigned short* yT     = (unsigned short*)(base + regB);
    unsigned short* Sb = (unsigned short*)out;   // bf16 S scores in d_out (dead before gcn)

    // optional aux region: bf16 gcn (halves stacked-GEMM write + k_final read).
    size_t gcn_bytes = (size_t)B_ * N_ * CT_ * 2;
    int use_aux = (ws_size >= o + gcn_bytes + 256) ? 1 : 0;
    unsigned short* gcnb = use_aux ? (unsigned short*)(base + alloc(gcn_bytes)) : nullptr;
    void* gcn_ptr = use_aux ? (void*)gcnb : (void*)out;
    const void* sgin = use_aux ? (const void*)gcnb : (const void*)out;

    dim3 b256(256);
    k_cvt_bf<<<dim3(N_ * N_ / 256), b256, 0, stream>>>(V_s, V_sb);
    k_cvt_bf<<<dim3(3 * N_ * N_ / 256), b256, 0, stream>>>(cheb, chb);
    k_wcat<<<dim3((F_ * 256 + 255) / 256), b256, 0, stream>>>(tc_w, rc_w, Wcat);
    k_thp<<<dim3((192 * 64 + 255) / 256), b256, 0, stream>>>(Theta, Thp);
    k_xreduce<<<dim3(N_ / 32, B_), b256, 0, stream>>>(x, U1, U3, rhs_t, partial);
    k_lhs_reduce<<<dim3((B_ * CT_ + 255) / 256), b256, 0, stream>>>(partial, lhs_t0);
    k_lhs_t<<<dim3((B_ * T_ * N_) / 256), b256, 0, stream>>>(lhs_t0, U2, lhs_t);
    k_prodt<<<dim3(8, B_), dim3(576), 0, stream>>>(lhs_t, rhs_t, ptp);
    k_temporal_E<<<dim3(B_), dim3(576), 0, stream>>>(ptp, b_e, V_e, Ebuf);
    k_tspatial<<<dim3(N_ / 4, B_), b256, 0, stream>>>(x, Ebuf, W1, W2, W3,
                                                      lhs_s, rhs_s, xTt);
    k_sig<<<dim3(N_ / 256, N_ / 64, B_), b256, 0, stream>>>(lhs_s, rhs_s, b_s, sigA);
    // S0 GEMM: M=1024, Ncols=1024, K=1024; bf16 C; nwg=512 (%8==0)
    k_gemm256<<<dim3(B_ * 4 * 4), dim3(512), 0, stream>>>(
        sigA, N_, (long)N_ * N_, V_sb, N_, 0, Sb, N_, (long)N_ * N_, N_, 4, 4, 1);
    k_smstats<<<dim3(N_ / 64, B_), b256, 0, stream>>>(Sb, mstats);
    k_yTmm<<<dim3(N_ / 128, B_ * T_), b256, 0, stream>>>(xTt, Thp, yT);        // sigA dead
    k_chebSt<<<dim3(N_ / 64, N_ / 64, B_), b256, 0, stream>>>(chb, Sb, mstats, chebSt); // xTt dead
    // stacked GEMM: M=1024, Ncols=1536, K=3072; nwg=768 (%8==0); bf16 C if aux fits
    k_gemm256<<<dim3(B_ * 4 * 6), dim3(512), 0, stream>>>(
        chebSt, KS_, (long)N_ * KS_, yT, KS_, (long)CT_ * KS_,
        gcn_ptr, CT_, (long)N_ * CT_, KS_, 6, 4, use_aux);                    // Sb dead
    k_final<<<dim3(N_ / 4, B_), b256, 0, stream>>>(x, sgin, use_aux, Wcat, tc_b, rc_b,
                                                   ln_g, ln_b, out);
}

// Round 17
// 980.211 us; speedup vs baseline: 3.1725x; 1.0140x over previous
//
#include <hip/hip_runtime.h>

typedef __attribute__((ext_vector_type(8))) short short8;   // 8 bf16 (4 VGPRs)
typedef __attribute__((ext_vector_type(4))) float f32x4;
typedef __attribute__((ext_vector_type(4))) unsigned short ushort4_;

constexpr int B_ = 32;
constexpr int N_ = 1024;
constexpr int C_ = 64;
constexpr int T_ = 24;
constexpr int F_ = 64;
constexpr int CT_ = C_ * T_;     // 1536
constexpr int KS_ = 3072;        // stacked K = 3*1024

__device__ __forceinline__ float sigmoidf_(float x) {
    return 1.0f / (1.0f + __expf(-x));
}
__device__ __forceinline__ unsigned short f2b(float f) {   // RNE f32->bf16
    union { float f; unsigned u; } v; v.f = f;
    unsigned r = v.u + 0x7FFFu + ((v.u >> 16) & 1u);
    return (unsigned short)(r >> 16);
}
__device__ __forceinline__ float b2f(unsigned short h) {
    union { unsigned u; float f; } v; v.u = ((unsigned)h) << 16; return v.f;
}
__device__ __forceinline__ void gload_lds16(const unsigned short* g, unsigned short* l) {
    __builtin_amdgcn_global_load_lds(
        (const __attribute__((address_space(1))) unsigned int*)g,
        (__attribute__((address_space(3))) unsigned int*)l, 16, 0, 0);
}

// ---------------- merged prep: V_s->bf16, cheb->bf16, Wcat, Thp (one launch) ----------
__global__ void k_prep(const float* __restrict__ V_s, const float* __restrict__ cheb,
                       const float* __restrict__ tc_w, const float* __restrict__ rc_w,
                       const float* __restrict__ Theta,
                       unsigned short* __restrict__ V_sb, unsigned short* __restrict__ chb,
                       unsigned short* __restrict__ Wcat, unsigned short* __restrict__ Thp) {
    int i = blockIdx.x * 256 + threadIdx.x;
    const int NV = N_ * N_;
    const int NC = 3 * N_ * N_;
    const int NW = F_ * 256;
    const int NT = 192 * 64;
    if (i < NV) { V_sb[i] = f2b(V_s[i]); return; }
    i -= NV;
    if (i < NC) { chb[i] = f2b(cheb[i]); return; }
    i -= NC;
    if (i < NW) {
        int ft = i >> 8, k = i & 255;
        int sel = k >> 6, c = k & 63;
        float v = (sel < 3) ? tc_w[(ft * C_ + c) * 3 + sel] : rc_w[ft * C_ + c];
        Wcat[i] = f2b(v);
        return;
    }
    i -= NW;
    if (i < NT) {
        int kf = i >> 6, c = i & 63;
        int k = kf >> 6, f = kf & 63;
        Thp[i] = f2b(Theta[((size_t)k * 64 + c) * 64 + f]);
    }
}

// ---------------- fused x reductions: rhs_t + U1-partial (one x read) ----------------
__global__ __launch_bounds__(256) void k_xreduce(const float* __restrict__ x,
        const float* __restrict__ U1, const float* __restrict__ U3,
        float* __restrict__ rhs_t, float* __restrict__ partial) {
    int b = blockIdx.y, g0 = blockIdx.x * 32;
    int tid = threadIdx.x;
    __shared__ float xr[8 * CT_];                        // 48 KB
    __shared__ float u3s[C_];
    if (tid < C_) u3s[tid] = U3[tid];
    float pacc[6] = {0, 0, 0, 0, 0, 0};
    for (int ph = 0; ph < 4; ++ph) {
        int n0 = g0 + ph * 8;
        __syncthreads();                                 // prev phase LDS reads done
        const float4* x4 = (const float4*)(x + ((size_t)(b * N_ + n0)) * CT_);
#pragma unroll
        for (int e = 0; e < 12; ++e) {
            int i4 = e * 256 + tid;
            float4 v = x4[i4];
            int i = i4 * 4;
            xr[i] = v.x; xr[i + 1] = v.y; xr[i + 2] = v.z; xr[i + 3] = v.w;
        }
        __syncthreads();
        if (tid < 192) {
            int n = tid / 24, t = tid % 24;
            const float* xn = xr + n * CT_ + t;
            float acc = 0.f;
#pragma unroll
            for (int c = 0; c < C_; ++c) acc += u3s[c] * xn[c * 24];
            rhs_t[((size_t)(b * N_ + n0 + n)) * T_ + t] = acc;
        }
#pragma unroll
        for (int n = 0; n < 8; ++n) {
            float u = U1[n0 + n];                        // uniform -> scalar
            const float* xn = xr + n * CT_;
#pragma unroll
            for (int e = 0; e < 6; ++e) pacc[e] += u * xn[tid + e * 256];
        }
    }
    float* pp = partial + ((size_t)(b * 32 + blockIdx.x)) * CT_;
#pragma unroll
    for (int e = 0; e < 6; ++e) pp[tid + e * 256] = pacc[e];
}

__global__ void k_lhs_reduce(const float* __restrict__ partial, float* __restrict__ lhs_t0) {
    int idx = blockIdx.x * 256 + threadIdx.x;
    if (idx >= B_ * CT_) return;
    int b = idx / CT_, flat = idx % CT_;
    float acc = 0.f;
#pragma unroll
    for (int ch = 0; ch < 32; ++ch) acc += partial[((size_t)(b * 32 + ch)) * CT_ + flat];
    lhs_t0[idx] = acc;
}

__global__ void k_lhs_t(const float* __restrict__ lhs_t0, const float* __restrict__ U2,
                        float* __restrict__ lhs_t) {
    int idx = blockIdx.x * 256 + threadIdx.x;
    if (idx >= B_ * T_ * N_) return;
    int n2 = idx % N_;
    int t = (idx / N_) % T_;
    int b = idx / (T_ * N_);
    const float* l0 = lhs_t0 + (size_t)b * CT_;
    float acc = 0.f;
#pragma unroll
    for (int c = 0; c < C_; ++c) acc += l0[c * T_ + t] * U2[c * N_ + n2];
    lhs_t[idx] = acc;
}

// prod_t partials: ptp[b][ch][i][u] = sum_{n in ch} lhs_t[b,i,n]*rhs_t[b,n,u]
__global__ __launch_bounds__(576) void k_prodt(const float* __restrict__ lhs_t,
        const float* __restrict__ rhs_t, float* __restrict__ ptp) {
    int b = blockIdx.y, ch = blockIdx.x;
    int tid = threadIdx.x;
    __shared__ float lt[24][128];
    __shared__ float rt[128][25];
    int n0 = ch * 128;
    for (int e = tid; e < 24 * 128; e += 576) {
        int i = e >> 7, nn = e & 127;
        lt[i][nn] = lhs_t[((size_t)b * T_ + i) * N_ + n0 + nn];
    }
    const float* rg = rhs_t + ((size_t)b * N_ + n0) * T_;
    for (int e = tid; e < 128 * 24; e += 576) {
        int nn = e / 24, t = e - nn * 24;
        rt[nn][t] = rg[e];
    }
    __syncthreads();
    int i = tid / 24, u = tid - (tid / 24) * 24;
    float acc = 0.f;
#pragma unroll 8
    for (int nn = 0; nn < 128; ++nn) acc += lt[i][nn] * rt[nn][u];
    ptp[(((size_t)b * 8 + ch) * 24 + i) * 24 + u] = acc;
}

__global__ void k_temporal_E(const float* __restrict__ ptp,
                             const float* __restrict__ b_e, const float* __restrict__ V_e,
                             float* __restrict__ E) {
    int b = blockIdx.x;
    int tid = threadIdx.x;                               // 576 threads
    int i = tid / T_, u = tid % T_;
    __shared__ float sig[T_][T_];
    __shared__ float e0s[T_][T_];
    __shared__ float mcol[T_], scol[T_];
    float acc = 0.f;
#pragma unroll
    for (int ch = 0; ch < 8; ++ch)
        acc += ptp[(((size_t)b * 8 + ch) * 24 + i) * 24 + u];
    sig[i][u] = sigmoidf_(acc + b_e[i * T_ + u]);
    __syncthreads();
    int j = u;
    float e0 = 0.f;
#pragma unroll
    for (int kk = 0; kk < T_; ++kk) e0 += sig[i][kk] * V_e[j * T_ + kk];
    e0s[i][j] = e0;
    __syncthreads();
    if (tid < T_) {
        float mx = -1e30f;
        for (int ii = 0; ii < T_; ++ii) mx = fmaxf(mx, e0s[ii][tid]);
        float s = 0.f;
        for (int ii = 0; ii < T_; ++ii) s += __expf(e0s[ii][tid] - mx);
        mcol[tid] = mx; scol[tid] = s;
    }
    __syncthreads();
    E[(size_t)b * T_ * T_ + i * T_ + j] = __expf(e0s[i][j] - mcol[j]) / scol[j];
}

// ---------------- fused: x_TAt (in-register) -> spatial prep + xTt emit ----------------
__global__ __launch_bounds__(256) void k_tspatial(const float* __restrict__ x,
        const float* __restrict__ E, const float* __restrict__ W1g,
        const float* __restrict__ W2, const float* __restrict__ W3g,
        float* __restrict__ lhs_s, float* __restrict__ rhs_s,
        unsigned short* __restrict__ xTt) {
    int b = blockIdx.y;
    int n0 = blockIdx.x * 4;
    int tid = threadIdx.x;
    __shared__ float Es[T_ * T_];
    __shared__ float W1s[T_];
    __shared__ float W2s[C_ * T_];
    __shared__ float xr[4][64][25];                      // staged x, then reused for w3*u
    __shared__ float l0s[4][64];
    for (int e = tid; e < T_ * T_; e += 256) Es[e] = E[(size_t)b * T_ * T_ + e];
    for (int e = tid; e < C_ * T_; e += 256) W2s[e] = W2[e];
    if (tid < T_) W1s[tid] = W1g[tid];
    size_t base = ((size_t)b * N_ + n0) * CT_;
    const float4* x4 = (const float4*)(x + base);
#pragma unroll
    for (int i = 0; i < 6; ++i) {
        int e4 = i * 256 + tid;
        float4 v = x4[e4];
        int e = e4 * 4;
        int nl = e / CT_; int rem = e - nl * CT_; int c = rem / 24; int tl = rem - c * 24;
        xr[nl][c][tl] = v.x; xr[nl][c][tl + 1] = v.y;
        xr[nl][c][tl + 2] = v.z; xr[nl][c][tl + 3] = v.w;
    }
    __syncthreads();
    int nl = tid >> 6, c = tid & 63;
    float xv[T_];
#pragma unroll
    for (int t = 0; t < T_; ++t) xv[t] = xr[nl][c][t];
    // emit xTt[b][t][n][c] bf16 from staged x (coalesced 128B chunks)
#pragma unroll
    for (int i = 0; i < 24; ++i) {
        int idx = i * 256 + tid;
        int cc = idx & 63, nn = (idx >> 6) & 3, t = idx >> 8;
        xTt[((size_t)(b * T_ + t) * N_ + n0 + nn) * 64 + cc] = f2b(xr[nn][cc][t]);
    }
    float w3 = W3g[c];
    float u[T_];
#pragma unroll
    for (int j = 0; j < T_; ++j) {
        float a = 0.f;
#pragma unroll
        for (int t = 0; t < T_; ++t) a += xv[t] * Es[t * T_ + j];
        u[j] = a;
    }
    float l0 = 0.f;
#pragma unroll
    for (int j = 0; j < T_; ++j) l0 += u[j] * W1s[j];
    __syncthreads();                                     // xTt-emit LDS reads done
#pragma unroll
    for (int j = 0; j < T_; ++j) xr[nl][c][j] = w3 * u[j];
    l0s[nl][c] = l0;
    __syncthreads();
    if (tid < 4 * T_) {
        int t = tid % T_, g = tid / T_;
        float racc = 0.f, lacc = 0.f;
        for (int cc = 0; cc < 64; ++cc) {
            racc += xr[g][cc][t];
            lacc += l0s[g][cc] * W2s[cc * T_ + t];
        }
        rhs_s[((size_t)b * T_ + t) * N_ + n0 + g] = racc;
        lhs_s[((size_t)(b * N_ + n0 + g)) * T_ + t] = lacc;
    }
}

// sigA[b][i][k] (bf16) = sigmoid(dot24(lhs_s[b,i,:], rhs_s[b,:,k]) + b_s[i,k])
__global__ __launch_bounds__(256) void k_sig(const float* __restrict__ lhs_s,
        const float* __restrict__ rhs_s, const float* __restrict__ b_s,
        unsigned short* __restrict__ sigA) {
    int b = blockIdx.z, i0 = blockIdx.y * 64, k0 = blockIdx.x * 256;
    int tid = threadIdx.x;
    __shared__ float lh[64 * T_];
    __shared__ float rh[T_][256];
    for (int e = tid; e < 64 * T_; e += 256) lh[e] = lhs_s[((size_t)b * N_ + i0) * T_ + e];
#pragma unroll
    for (int t = 0; t < T_; ++t) rh[t][tid] = rhs_s[((size_t)b * T_ + t) * N_ + k0 + tid];
    __syncthreads();
    int kg = k0 + tid;
    for (int ii = 0; ii < 64; ++ii) {
        float acc = b_s[(size_t)(i0 + ii) * N_ + kg];
#pragma unroll
        for (int t = 0; t < T_; ++t) acc += lh[ii * T_ + t] * rh[t][tid];
        sigA[((size_t)b * N_ + i0 + ii) * N_ + kg] = f2b(sigmoidf_(acc));
    }
}

// ---------------- yT via MFMA, coalesced stores through LDS C-tile ----------------
__global__ __launch_bounds__(256) void k_yTmm(const unsigned short* __restrict__ xTt,
        const unsigned short* __restrict__ Thp, unsigned short* __restrict__ yT) {
    int bt = blockIdx.y;
    int b = bt / T_, t = bt - b * T_;
    int m0 = blockIdx.x * 128;
    int tid = threadIdx.x;
    int lane = tid & 63, wv = tid >> 6;
    __shared__ __align__(16) char smem[50688];
    unsigned short* Asb = (unsigned short*)smem;             // [192*64] (live whole kernel)
    unsigned short* Bsb = (unsigned short*)(smem + 24576);   // [128*64]
    unsigned short* Cl  = (unsigned short*)(smem + 24576);   // [96][136] (after Bsb dead)
#pragma unroll
    for (int e = 0; e < 6; ++e) {                        // stage Thp (24KB)
        int chunk = e * 256 + tid;
        int row = chunk >> 3, slot = chunk & 7;
        int gslot = slot ^ (row & 7);
        gload_lds16(Thp + row * 64 + gslot * 8, &Asb[chunk * 8]);
    }
    const unsigned short* Bg = xTt + ((size_t)bt * N_ + m0) * 64;
#pragma unroll
    for (int e = 0; e < 4; ++e) {                        // stage B (16KB)
        int chunk = e * 256 + tid;
        int row = chunk >> 3, slot = chunk & 7;
        int gslot = slot ^ (row & 7);
        gload_lds16(Bg + (size_t)row * 64 + gslot * 8, &Bsb[chunk * 8]);
    }
    __syncthreads();                                     // drains vmcnt

    short8 bf[2][2];
#pragma unroll
    for (int ni = 0; ni < 2; ++ni)
#pragma unroll
        for (int kk = 0; kk < 2; ++kk) {
            int r = wv * 32 + ni * 16 + (lane & 15);
            int slot = (kk * 4 + (lane >> 4)) ^ (r & 7);
            bf[ni][kk] = *(const short8*)&Bsb[r * 64 + slot * 8];
        }
    f32x4 acc[12][2];
#pragma unroll
    for (int mi = 0; mi < 12; ++mi)
#pragma unroll
        for (int ni = 0; ni < 2; ++ni) acc[mi][ni] = (f32x4){0.f, 0.f, 0.f, 0.f};
#pragma unroll
    for (int mi = 0; mi < 12; ++mi) {
        short8 af[2];
#pragma unroll
        for (int kk = 0; kk < 2; ++kk) {
            int r = mi * 16 + (lane & 15);
            int slot = (kk * 4 + (lane >> 4)) ^ (r & 7);
            af[kk] = *(const short8*)&Asb[r * 64 + slot * 8];
        }
#pragma unroll
        for (int kk = 0; kk < 2; ++kk)
#pragma unroll
            for (int ni = 0; ni < 2; ++ni)
                acc[mi][ni] = __builtin_amdgcn_mfma_f32_16x16x32_bf16(
                    af[kk], bf[ni][kk], acc[mi][ni], 0, 0, 0);
    }
#pragma unroll
    for (int h = 0; h < 2; ++h) {
        __syncthreads();
#pragma unroll
        for (int mi2 = 0; mi2 < 6; ++mi2) {
            int mi = h * 6 + mi2;
#pragma unroll
            for (int r = 0; r < 4; ++r) {
                int row = mi2 * 16 + (lane >> 4) * 4 + r;
#pragma unroll
                for (int ni = 0; ni < 2; ++ni)
                    Cl[row * 136 + wv * 32 + ni * 16 + (lane & 15)] = f2b(acc[mi][ni][r]);
            }
        }
        __syncthreads();
#pragma unroll
        for (int e = 0; e < 6; ++e) {
            int idx = e * 256 + tid;
            int row = idx >> 4, seg = idx & 15;
            int kf = h * 96 + row;
            int k = kf >> 6, f = kf & 63;
            uint4 v = *(const uint4*)&Cl[row * 136 + seg * 8];
            *(uint4*)&yT[((size_t)b * CT_ + f * T_ + t) * KS_ + k * N_ + m0 + seg * 8] = v;
        }
    }
}

// online softmax stats over axis m of S[b,m,i] (bf16): mst[b*N+i] = (max, 1/sum)
__global__ void k_smstats(const unsigned short* __restrict__ S, float2* __restrict__ mst) {
    int b = blockIdx.y;
    int jj = threadIdx.x % 64;
    int ig = threadIdx.x / 64;
    int j = blockIdx.x * 64 + jj;
    __shared__ float rm[4][64], rs[4][64];
    float m = -1e30f, s = 0.f;
    for (int i = ig; i < N_; i += 4) {
        float v = b2f(S[((size_t)b * N_ + i) * N_ + j]);
        float mn = fmaxf(m, v);
        s = s * __expf(m - mn) + __expf(v - mn);
        m = mn;
    }
    rm[ig][jj] = m; rs[ig][jj] = s;
    __syncthreads();
    if (ig == 0) {
        float M = rm[0][jj], SS = rs[0][jj];
#pragma unroll
        for (int g = 1; g < 4; ++g) {
            float mg = rm[g][jj];
            float mn = fmaxf(M, mg);
            SS = SS * __expf(M - mn) + rs[g][jj] * __expf(mg - mn);
            M = mn;
        }
        mst[(size_t)b * N_ + j] = make_float2(M, 1.f / SS);
    }
}

// chebSt[b][i][k*1024+m] (bf16) = chb[k][m][i] * softmax(S)[b][m][i]  (bf16 reads)
__global__ __launch_bounds__(256) void k_chebSt(const unsigned short* __restrict__ chb,
        const unsigned short* __restrict__ S, const float2* __restrict__ mst,
        unsigned short* __restrict__ cs) {
    int b = blockIdx.z, i0 = blockIdx.y * 64, m0 = blockIdx.x * 64;
    int tid = threadIdx.x;
    __shared__ float st[64][65];
    __shared__ float cb[64][65];
    __shared__ float2 sst[64];
    if (tid < 64) sst[tid] = mst[(size_t)b * N_ + i0 + tid];
#pragma unroll
    for (int e = 0; e < 4; ++e) {
        int idx4 = e * 256 + tid;
        int mm = idx4 >> 4, ii0 = (idx4 & 15) * 4;
        ushort4_ v = *(const ushort4_*)&S[((size_t)b * N_ + m0 + mm) * N_ + i0 + ii0];
        st[mm][ii0] = b2f(v.x); st[mm][ii0 + 1] = b2f(v.y);
        st[mm][ii0 + 2] = b2f(v.z); st[mm][ii0 + 3] = b2f(v.w);
    }
    for (int k = 0; k < 3; ++k) {
        __syncthreads();
#pragma unroll
        for (int e = 0; e < 4; ++e) {
            int idx4 = e * 256 + tid;
            int mm = idx4 >> 4, ii0 = (idx4 & 15) * 4;
            ushort4_ v = *(const ushort4_*)&chb[((size_t)k * N_ + m0 + mm) * N_ + i0 + ii0];
            cb[mm][ii0] = b2f(v.x); cb[mm][ii0 + 1] = b2f(v.y);
            cb[mm][ii0 + 2] = b2f(v.z); cb[mm][ii0 + 3] = b2f(v.w);
        }
        __syncthreads();
#pragma unroll
        for (int e = 0; e < 16; ++e) {
            int idx = e * 256 + tid; int mm = idx & 63, ii = idx >> 6;
            float sm = __expf(st[mm][ii] - sst[ii].x) * sst[ii].y;
            cs[((size_t)b * N_ + i0 + ii) * KS_ + k * N_ + m0 + mm] =
                f2b(sm * cb[mm][ii]);
        }
    }
}

// ---------------- 256x256-tile MFMA GEMM, hybrid counted-vmcnt pipeline (R14) ----------
// obf: 0 -> f32 C, 1 -> bf16 C (ldc in elements either way)
__global__ __launch_bounds__(512, 2) void k_gemm256(
        const unsigned short* __restrict__ A, long lda, long sA,
        const unsigned short* __restrict__ Bt, long ldb, long sB,
        void* __restrict__ Cc, long ldc, long sC, int K, int nbx, int nby, int obf) {
    __shared__ __align__(16) unsigned short As[2][256 * 64];   // 2 x 32KB
    __shared__ __align__(16) unsigned short Bs[2][256 * 64];   // 2 x 32KB
    int tid = threadIdx.x;
    int lane = tid & 63, w = tid >> 6;
    int wy = w >> 2, wx = w & 3;                            // 2 x 4 waves -> 128x64 per wave

    int nwg = gridDim.x;
    int cpx = nwg >> 3;
    int logical = (blockIdx.x & 7) * cpx + (blockIdx.x >> 3);
    int tpb = nbx * nby;
    int b = logical / tpb;
    int tile = logical % tpb;
    int i0 = (tile / nbx) * 256;
    int j0 = (tile % nbx) * 256;

    const unsigned short* Ab = A + (size_t)b * sA + (size_t)i0 * lda;
    const unsigned short* Bb = Bt + (size_t)b * sB + (size_t)j0 * ldb;

    auto STAGE = [&](int kt, int d) {
        int kof = kt << 6;
#pragma unroll
        for (int e = 0; e < 4; ++e) {
            int chunk = e * 512 + tid;
            int row = chunk >> 3, slot = chunk & 7;
            int gslot = slot ^ (row & 7);                   // inverse swizzle on source
            gload_lds16(Ab + (size_t)row * lda + kof + gslot * 8, &As[d][chunk * 8]);
        }
#pragma unroll
        for (int e = 0; e < 4; ++e) {
            int chunk = e * 512 + tid;
            int row = chunk >> 3, slot = chunk & 7;
            int gslot = slot ^ (row & 7);
            gload_lds16(Bb + (size_t)row * ldb + kof + gslot * 8, &Bs[d][chunk * 8]);
        }
    };
    auto READF = [&](short8* af, short8* bfv,
                     const unsigned short* Asb, const unsigned short* Bsb, int kkb) {
#pragma unroll
        for (int mi = 0; mi < 8; ++mi) {
            int r = wy * 128 + mi * 16 + (lane & 15);
            int slot = (kkb + (lane >> 4)) ^ (r & 7);
            af[mi] = *(const short8*)&Asb[r * 64 + slot * 8];
        }
#pragma unroll
        for (int ni = 0; ni < 4; ++ni) {
            int r = wx * 64 + ni * 16 + (lane & 15);
            int slot = (kkb + (lane >> 4)) ^ (r & 7);
            bfv[ni] = *(const short8*)&Bsb[r * 64 + slot * 8];
        }
    };

    f32x4 acc[8][4];
#pragma unroll
    for (int mi = 0; mi < 8; ++mi)
#pragma unroll
        for (int ni = 0; ni < 4; ++ni) acc[mi][ni] = (f32x4){0.f, 0.f, 0.f, 0.f};

    int nt = K >> 6;
    STAGE(0, 0);
    STAGE(1, 1);
    asm volatile("s_waitcnt vmcnt(8)" ::: "memory");        // K-tile 0 resident
    __builtin_amdgcn_s_barrier();
    __builtin_amdgcn_sched_barrier(0);

    short8 a0[8], b0[4], a1[8], b1[4];
    READF(a0, b0, As[0], Bs[0], 0);                         // kk0 of tile 0

    for (int kt = 0; kt < nt; ++kt) {
        int cur = kt & 1;
        READF(a1, b1, As[cur], Bs[cur], 4);                 // kk1 of this tile
        __builtin_amdgcn_s_setprio(1);
#pragma unroll
        for (int mi = 0; mi < 8; ++mi)
#pragma unroll
            for (int ni = 0; ni < 4; ++ni)
                acc[mi][ni] = __builtin_amdgcn_mfma_f32_16x16x32_bf16(
                    a0[mi], b0[ni], acc[mi][ni], 0, 0, 0);
        __builtin_amdgcn_s_setprio(0);
        asm volatile("s_waitcnt lgkmcnt(0)" ::: "memory");  // my reads of buf[cur] done
        __builtin_amdgcn_sched_barrier(0);
        __builtin_amdgcn_s_barrier();                       // all waves done with buf[cur]
        __builtin_amdgcn_sched_barrier(0);
        if (kt + 2 < nt) STAGE(kt + 2, cur);                // overwrite freed buffer
        __builtin_amdgcn_sched_barrier(0);
        __builtin_amdgcn_s_setprio(1);
#pragma unroll
        for (int mi = 0; mi < 8; ++mi)
#pragma unroll
            for (int ni = 0; ni < 4; ++ni)
                acc[mi][ni] = __builtin_amdgcn_mfma_f32_16x16x32_bf16(
                    a1[mi], b1[ni], acc[mi][ni], 0, 0, 0);
        __builtin_amdgcn_s_setprio(0);
        if (kt + 2 < nt) {
            asm volatile("s_waitcnt vmcnt(8)" ::: "memory"); // kt+1 retired, kt+2 in flight
        } else {
            asm volatile("s_waitcnt vmcnt(0)" ::: "memory"); // tail: drain (race-safe)
        }
        __builtin_amdgcn_s_barrier();                       // buf[cur^1] ready for all waves
        __builtin_amdgcn_sched_barrier(0);
        if (kt + 1 < nt)
            READF(a0, b0, As[cur ^ 1], Bs[cur ^ 1], 0);     // kk0 of next tile
    }

    if (obf) {
        unsigned short* Cb = (unsigned short*)Cc + (size_t)b * sC;
#pragma unroll
        for (int mi = 0; mi < 8; ++mi) {
#pragma unroll
            for (int r = 0; r < 4; ++r) {
                int i = i0 + wy * 128 + mi * 16 + (lane >> 4) * 4 + r;
                unsigned short* cp = Cb + (size_t)i * ldc + j0 + wx * 64 + (lane & 15);
#pragma unroll
                for (int ni = 0; ni < 4; ++ni) cp[ni * 16] = f2b(acc[mi][ni][r]);
            }
        }
    } else {
        float* Cb = (float*)Cc + (size_t)b * sC;
#pragma unroll
        for (int mi = 0; mi < 8; ++mi) {
#pragma unroll
            for (int r = 0; r < 4; ++r) {
                int i = i0 + wy * 128 + mi * 16 + (lane >> 4) * 4 + r;
                float* cp = Cb + (size_t)i * ldc + j0 + wx * 64 + (lane & 15);
#pragma unroll
                for (int ni = 0; ni < 4; ++ni) cp[ni * 16] = acc[mi][ni][r];
            }
        }
    }
}

// ---------------- fused epilogue via MFMA; sbf: bf16/f32 gcn; xbf: bf16 xTt / f32 x ------
__global__ __launch_bounds__(256) void k_final(const float* __restrict__ x,
        const unsigned short* __restrict__ xtp, int xbf,
        const void* __restrict__ sgin, int sbf, const unsigned short* __restrict__ Wcat,
        const float* __restrict__ tc_b, const float* __restrict__ rc_b,
        const float* __restrict__ ln_g, const float* __restrict__ ln_b,
        float* __restrict__ out) {
    int b = blockIdx.y;
    int n0 = blockIdx.x * 4;
    int tid = threadIdx.x;
    int lane = tid & 63, wv = tid >> 6;

    __shared__ __align__(16) char smem[25600];
    unsigned short* sgb = (unsigned short*)smem;            // [4][26][64]
    unsigned short* xb  = (unsigned short*)(smem + 13312);  // [4][24][64]
    float* Cl = (float*)smem;                               // [96][66] (after reuse barrier)
    __shared__ float tbs[64], gs[64], bbs[64];
    __shared__ float mus[96], rss[96];

    if (tid < 64) {
        tbs[tid] = tc_b[tid] + rc_b[tid];
        gs[tid] = ln_g[tid];
        bbs[tid] = ln_b[tid];
    }
    for (int e = tid; e < 512; e += 256) {
        int nl = e >> 7, r = (e >> 6) & 1, c = e & 63;
        int tt = r ? 25 : 0;
        sgb[(nl * 26 + tt) * 64 + (((c >> 3) ^ (tt & 7)) << 3) + (c & 7)] = 0;
    }
    size_t base = ((size_t)b * N_ + n0) * CT_;
    if (xbf) {                                          // x staging from bf16 xTt
        // xTt[b][t][n0+nn][c]: per (t,nn) 128B contiguous; uint4 = 8 bf16
        const uint4* xt4 = (const uint4*)xtp;
        size_t base4 = ((size_t)(b * T_) * N_ + n0) * 8;  // uint4 units
#pragma unroll
        for (int i = 0; i < 3; ++i) {
            int e = i * 256 + tid;                      // 768 uint4 total
            int t = e >> 5;                             // 32 uint4 per t
            int u8 = e & 31;
            int nn = u8 >> 3, c8 = u8 & 7;
            uint4 v = xt4[base4 + ((size_t)t * N_ + nn) * 8 + c8];
            *(uint4*)&xb[(nn * 24 + t) * 64 + ((c8 ^ (t & 7)) << 3)] = v;
        }
    } else {                                            // x staging from f32 x
        const float4* xg4 = (const float4*)(x + base);
#pragma unroll
        for (int i = 0; i < 6; ++i) {
            int e4 = i * 256 + tid;
            float4 xv4 = xg4[e4];
            int e = e4 * 4;
            int nl = e / CT_;
            int rem = e - nl * CT_;
            int c = rem / 24;
            int tl = rem - c * 24;
            float xv[4] = {xv4.x, xv4.y, xv4.z, xv4.w};
#pragma unroll
            for (int j = 0; j < 4; ++j) {
                int tj = tl + j;
                xb[(nl * 24 + tj) * 64 + (((c >> 3) ^ (tj & 7)) << 3) + (c & 7)] = f2b(xv[j]);
            }
        }
    }
    if (sbf) {                                          // gcn staging (bf16 input)
        const uint4* sg8 = (const uint4*)((const unsigned short*)sgin + base);
#pragma unroll
        for (int i = 0; i < 3; ++i) {
            int e8 = i * 256 + tid;
            uint4 v = sg8[e8];
            const unsigned short* sp = (const unsigned short*)&v;
            int e = e8 * 8;
            int nl = e / CT_;
            int rem = e - nl * CT_;
            int c = rem / 24;
            int tl = rem - c * 24;                       // tl in {0,8,16}
#pragma unroll
            for (int j = 0; j < 8; ++j) {
                int tt = tl + j + 1;
                unsigned short sb = sp[j];
                sgb[(nl * 26 + tt) * 64 + (((c >> 3) ^ (tt & 7)) << 3) + (c & 7)] =
                    (sb & 0x8000u) ? (unsigned short)0 : sb;   // relu on bf16 bits
            }
        }
    } else {                                            // gcn staging (f32 input)
        const float4* sg4 = (const float4*)((const float*)sgin + base);
#pragma unroll
        for (int i = 0; i < 6; ++i) {
            int e4 = i * 256 + tid;
            float4 sv4 = sg4[e4];
            int e = e4 * 4;
            int nl = e / CT_;
            int rem = e - nl * CT_;
            int c = rem / 24;
            int tl = rem - c * 24;
            float sv[4] = {sv4.x, sv4.y, sv4.z, sv4.w};
#pragma unroll
            for (int j = 0; j < 4; ++j) {
                int tt = tl + j + 1;
                sgb[(nl * 26 + tt) * 64 + (((c >> 3) ^ (tt & 7)) << 3) + (c & 7)] =
                    f2b(fmaxf(sv[j], 0.f));
            }
        }
    }

    int ft = wv * 16 + (lane & 15);
    int g4 = lane >> 4;
    short8 bfr[8];
#pragma unroll
    for (int ks = 0; ks < 8; ++ks)
        bfr[ks] = *(const short8*)&Wcat[ft * 256 + ks * 32 + g4 * 8];

    int rnl[6], rt[6];
#pragma unroll
    for (int mi = 0; mi < 6; ++mi) {
        int row = mi * 16 + (lane & 15);
        rnl[mi] = row / 24;
        rt[mi] = row - rnl[mi] * 24;
    }

    __syncthreads();

    f32x4 acc[6];
#pragma unroll
    for (int mi = 0; mi < 6; ++mi) acc[mi] = (f32x4){0.f, 0.f, 0.f, 0.f};
#pragma unroll
    for (int mi = 0; mi < 6; ++mi) {
        int nl = rnl[mi], t = rt[mi];
#pragma unroll
        for (int ks = 0; ks < 8; ++ks) {
            const int sel = ks >> 1;
            int slot = (ks & 1) * 4 + g4;
            short8 af;
            if (sel < 3) {
                int tt = t + sel;
                af = *(const short8*)&sgb[(nl * 26 + tt) * 64 + ((slot ^ (tt & 7)) << 3)];
            } else {
                af = *(const short8*)&xb[(nl * 24 + t) * 64 + ((slot ^ (t & 7)) << 3)];
            }
            acc[mi] = __builtin_amdgcn_mfma_f32_16x16x32_bf16(af, bfr[ks], acc[mi], 0, 0, 0);
        }
    }

    __syncthreads();
#pragma unroll
    for (int mi = 0; mi < 6; ++mi)
#pragma unroll
        for (int r = 0; r < 4; ++r)
            Cl[(mi * 16 + (lane >> 4) * 4 + r) * 66 + wv * 16 + (lane & 15)] = acc[mi][r];
    __syncthreads();

    if (tid < 96) {
        float s = 0.f, s2 = 0.f;
#pragma unroll
        for (int f = 0; f < 64; ++f) {
            float v = fmaxf(Cl[tid * 66 + f] + tbs[f], 0.f);
            s += v; s2 += v * v;
        }
        float mu = s * (1.f / 64.f);
        float var = s2 * (1.f / 64.f) - mu * mu;
        mus[tid] = mu;
        rss[tid] = rsqrtf(var + 1e-5f);
    }
    __syncthreads();

    float4* o4 = (float4*)(out + base);
#pragma unroll
    for (int i = 0; i < 6; ++i) {
        int e4 = i * 256 + tid;
        int e = e4 * 4;
        int nl = e / CT_;
        int rem = e - nl * CT_;
        int f = rem / 24;
        int t0v = rem - f * 24;
        float g = gs[f], bb2 = bbs[f], tb2 = tbs[f];
        float vals[4];
#pragma unroll
        for (int j = 0; j < 4; ++j) {
            int row = nl * 24 + t0v + j;
            float v = fmaxf(Cl[row * 66 + f] + tb2, 0.f);
            vals[j] = (v - mus[row]) * rss[row] * g + bb2;
        }
        float4 r;
        r.x = vals[0]; r.y = vals[1]; r.z = vals[2]; r.w = vals[3];
        o4[e4] = r;
    }
}

extern "C" void kernel_launch(void* const* d_in, const int* in_sizes, int n_in,
                              void* d_out, int out_size, void* d_ws, size_t ws_size,
                              hipStream_t stream) {
    const float* x    = (const float*)d_in[0];
    const float* cheb = (const float*)d_in[1];
    const float* U1   = (const float*)d_in[2];
    const float* U2   = (const float*)d_in[3];
    const float* U3   = (const float*)d_in[4];
    const float* b_e  = (const float*)d_in[5];
    const float* V_e  = (const float*)d_in[6];
    const float* W1   = (const float*)d_in[7];
    const float* W2   = (const float*)d_in[8];
    const float* W3   = (const float*)d_in[9];
    const float* b_s  = (const float*)d_in[10];
    const float* V_s  = (const float*)d_in[11];
    const float* Theta= (const float*)d_in[12];
    const float* tc_w = (const float*)d_in[13];
    const float* tc_b = (const float*)d_in[14];
    const float* rc_w = (const float*)d_in[15];
    const float* rc_b = (const float*)d_in[16];
    const float* ln_g = (const float*)d_in[17];
    const float* ln_b = (const float*)d_in[18];
    float* out = (float*)d_out;

    char* base = (char*)d_ws;
    size_t o = 0;
    auto alloc = [&](size_t bytes) { size_t r = o; o += (bytes + 255) & ~(size_t)255; return r; };
    float* lhs_t   = (float*)(base + alloc((size_t)B_ * T_ * N_ * 4));
    float* rhs_t   = (float*)(base + alloc((size_t)B_ * N_ * T_ * 4));
    float* Ebuf    = (float*)(base + alloc((size_t)B_ * T_ * T_ * 4));
    float* partial = (float*)(base + alloc((size_t)B_ * 32 * CT_ * 4));
    float* ptp     = (float*)(base + alloc((size_t)B_ * 8 * T_ * T_ * 4));
    float* lhs_t0  = (float*)(base + alloc((size_t)B_ * CT_ * 4));
    float* lhs_s   = (float*)(base + alloc((size_t)B_ * N_ * T_ * 4));
    float* rhs_s   = (float*)(base + alloc((size_t)B_ * T_ * N_ * 4));
    unsigned short* V_sb = (unsigned short*)(base + alloc((size_t)N_ * N_ * 2));
    unsigned short* Wcat = (unsigned short*)(base + alloc((size_t)F_ * 256 * 2));
    unsigned short* Thp  = (unsigned short*)(base + alloc((size_t)192 * 64 * 2));
    unsigned short* chb  = (unsigned short*)(base + alloc((size_t)3 * N_ * N_ * 2));
    float2* mstats = (float2*)(base + alloc((size_t)B_ * N_ * 8));
    size_t regA = alloc((size_t)B_ * N_ * KS_ * 2);   // xTt (fallback) -> chebSt (bf16)
    size_t regB = alloc((size_t)B_ * CT_ * KS_ * 2);  // sigA (bf16) -> yT (bf16)
    unsigned short* chebSt = (unsigned short*)(base + regA);
    unsigned short* sigA   = (unsigned short*)(base + regB);
    unsigned short* yT     = (unsigned short*)(base + regB);
    unsigned short* Sb = (unsigned short*)out;   // bf16 S scores in d_out (dead before gcn)

    // aux region 1: bf16 gcn (halves stacked-GEMM write + k_final read).
    size_t gcn_bytes = (size_t)B_ * N_ * CT_ * 2;
    int use_aux = (ws_size >= o + gcn_bytes + 256) ? 1 : 0;
    unsigned short* gcnb = use_aux ? (unsigned short*)(base + alloc(gcn_bytes)) : nullptr;
    void* gcn_ptr = use_aux ? (void*)gcnb : (void*)out;
    const void* sgin = use_aux ? (const void*)gcnb : (const void*)out;

    // aux region 2: persistent xTt (k_final reads bf16 x instead of f32 x).
    size_t xtt_bytes = (size_t)B_ * T_ * N_ * 64 * 2;   // 96 MB
    int use_aux2 = (ws_size >= o + xtt_bytes + 256) ? 1 : 0;
    unsigned short* xTt = use_aux2 ? (unsigned short*)(base + alloc(xtt_bytes))
                                   : (unsigned short*)(base + regA);  // aliased by chebSt

    dim3 b256(256);
    int prep_n = N_ * N_ + 3 * N_ * N_ + F_ * 256 + 192 * 64;
    k_prep<<<dim3((prep_n + 255) / 256), b256, 0, stream>>>(
        V_s, cheb, tc_w, rc_w, Theta, V_sb, chb, Wcat, Thp);
    k_xreduce<<<dim3(N_ / 32, B_), b256, 0, stream>>>(x, U1, U3, rhs_t, partial);
    k_lhs_reduce<<<dim3((B_ * CT_ + 255) / 256), b256, 0, stream>>>(partial, lhs_t0);
    k_lhs_t<<<dim3((B_ * T_ * N_) / 256), b256, 0, stream>>>(lhs_t0, U2, lhs_t);
    k_prodt<<<dim3(8, B_), dim3(576), 0, stream>>>(lhs_t, rhs_t, ptp);
    k_temporal_E<<<dim3(B_), dim3(576), 0, stream>>>(ptp, b_e, V_e, Ebuf);
    k_tspatial<<<dim3(N_ / 4, B_), b256, 0, stream>>>(x, Ebuf, W1, W2, W3,
                                                      lhs_s, rhs_s, xTt);
    k_sig<<<dim3(N_ / 256, N_ / 64, B_), b256, 0, stream>>>(lhs_s, rhs_s, b_s, sigA);
    // S0 GEMM: M=1024, Ncols=1024, K=1024; bf16 C; nwg=512 (%8==0)
    k_gemm256<<<dim3(B_ * 4 * 4), dim3(512), 0, stream>>>(
        sigA, N_, (long)N_ * N_, V_sb, N_, 0, Sb, N_, (long)N_ * N_, N_, 4, 4, 1);
    k_smstats<<<dim3(N_ / 64, B_), b256, 0, stream>>>(Sb, mstats);
    k_yTmm<<<dim3(N_ / 128, B_ * T_), b256, 0, stream>>>(xTt, Thp, yT);        // sigA dead
    k_chebSt<<<dim3(N_ / 64, N_ / 64, B_), b256, 0, stream>>>(chb, Sb, mstats, chebSt);
    // stacked GEMM: M=1024, Ncols=1536, K=3072; nwg=768 (%8==0); bf16 C if aux fits
    k_gemm256<<<dim3(B_ * 4 * 6), dim3(512), 0, stream>>>(
        chebSt, KS_, (long)N_ * KS_, yT, KS_, (long)CT_ * KS_,
        gcn_ptr, CT_, (long)N_ * CT_, KS_, 6, 4, use_aux);                    // Sb dead
    k_final<<<dim3(N_ / 4, B_), b256, 0, stream>>>(x, xTt, use_aux2, sgin, use_aux,
                                                   Wcat, tc_b, rc_b, ln_g, ln_b, out);
}